// Round 10
// baseline (487.799 us; speedup 1.0000x reference)
//
#include <hip/hip_runtime.h>
#include <stdint.h>

// B=1, L=2048, DIM=1536, H=12, HD=128. Inputs f32, output f32 (verified R6).
// R16: __expf in softmax path => 523->472.8us, absmax bit-identical.
// R17: qkv wall re-derived: 4333 cy/K-iter vs ~1400 cy of work => latency-
// exposed low-TLP regime (VGPR 96 = W-prefetch not held; occupancy-relative
// evidence). Fix = shrink per-iter critical path + raise TLP, not reschedule:
// BN 128->64 on both GEMMs (24 MFMA/12 ds_read/1 split/2 W-loads per iter,
// LDS 64KB = clean 2 blocks/CU, grid 576->1152 / 192->384). Accumulation
// order per element unchanged => bit-identical (absmax 3.428459e-3).
// R18: byte-identical resubmit — R9 bench was an infra failure (container
// acquisition), kernel never ran; the R17 experiment is still pending.
#define SEQ 2048
#define DIM 1536
#define NH  12
#define HD  128
#define SCALEF 0.08838834764831845f  // 128^-0.5

typedef __attribute__((ext_vector_type(8))) short short8;
typedef __attribute__((ext_vector_type(4))) float floatx4;

#define MFMA16(a, b, c) __builtin_amdgcn_mfma_f32_16x16x32_bf16((a), (b), (c), 0, 0, 0)

__device__ __forceinline__ void async_cp16(const void* g, void* l) {
  __builtin_amdgcn_global_load_lds(
      (__attribute__((address_space(1))) unsigned int*)(g),
      (__attribute__((address_space(3))) unsigned int*)(l), 16, 0, 0);
}

__device__ __forceinline__ unsigned short f2bf(float f) {
  unsigned int u = __float_as_uint(f);
  u = (u + 0x7fff + ((u >> 16) & 1)) >> 16;  // RNE
  return (unsigned short)u;
}

// Split f32 -> hi (truncated bf16) + lo (RNE bf16 of residual).
__device__ __forceinline__ void split8v(const float* x, short8& h, short8& l) {
#pragma unroll
  for (int e = 0; e < 8; e++) {
    unsigned int u = __float_as_uint(x[e]);
    h[e] = (short)(u >> 16);
    float r = x[e] - __uint_as_float(u & 0xFFFF0000u);
    l[e] = (short)f2bf(r);
  }
}
__device__ __forceinline__ void split8(const float* g, short8& h, short8& l) {
  float4 f0 = *(const float4*)g, f1 = *(const float4*)(g + 4);
  float x[8] = {f0.x, f0.y, f0.z, f0.w, f1.x, f1.y, f1.z, f1.w};
  split8v(x, h, l);
}

__global__ __launch_bounds__(256) void k_fill(float* __restrict__ out, int n,
                                              float val) {
  int i = blockIdx.x * 256 + threadIdx.x;
  if (i < n) out[i] = val;
}

// ---------------------------------------------------------------------------
// K0a: pre-split X -> tiled bf16 planes. Tile (mb,ks) = 8KB contiguous,
// rows mb*128..+127 x k ks*32..+31, chunk-xor (p ^ (row>>1)&3) pre-applied.
// Grid: (48 ks, 16 mb).
// ---------------------------------------------------------------------------
__global__ __launch_bounds__(256) void k_split_x(
    const float* __restrict__ X, unsigned short* __restrict__ Xh,
    unsigned short* __restrict__ Xl) {
  int ks = blockIdx.x, mb = blockIdx.y, tid = threadIdx.x;
  size_t tb = ((size_t)mb * 48 + ks) * 4096;
#pragma unroll
  for (int i = 0; i < 2; i++) {
    int sidx = i * 256 + tid;
    int row = sidx >> 2, p = sidx & 3;
    int c = p ^ ((row >> 1) & 3);
    short8 h, l;
    split8(X + (size_t)(mb * 128 + row) * DIM + ks * 32 + c * 8, h, l);
    *(short8*)(Xh + tb + sidx * 8) = h;
    *(short8*)(Xl + tb + sidx * 8) = l;
  }
}

// ---------------------------------------------------------------------------
// K0b: pre-sum + split attn output -> tiled Oh/Ol (same layout as k_split_x).
// ---------------------------------------------------------------------------
__global__ __launch_bounds__(256) void k_split_o(
    const float* __restrict__ A0, const float* __restrict__ A1,
    unsigned short* __restrict__ Oh, unsigned short* __restrict__ Ol) {
  int ks = blockIdx.x, mb = blockIdx.y, tid = threadIdx.x;
  size_t tb = ((size_t)mb * 48 + ks) * 4096;
#pragma unroll
  for (int i = 0; i < 2; i++) {
    int sidx = i * 256 + tid;
    int row = sidx >> 2, p = sidx & 3;
    int c = p ^ ((row >> 1) & 3);
    size_t off = (size_t)(mb * 128 + row) * DIM + ks * 32 + c * 8;
    float4 x0 = *(const float4*)(A0 + off), x1 = *(const float4*)(A0 + off + 4);
    float4 y0 = *(const float4*)(A1 + off), y1 = *(const float4*)(A1 + off + 4);
    float xs[8] = {x0.x + y0.x, x0.y + y0.y, x0.z + y0.z, x0.w + y0.w,
                   x1.x + y1.x, x1.y + y1.y, x1.z + y1.z, x1.w + y1.w};
    short8 h, l;
    split8v(xs, h, l);
    *(short8*)(Oh + tb + sidx * 8) = h;
    *(short8*)(Ol + tb + sidx * 8) = l;
  }
}

// ---------------------------------------------------------------------------
// BN=64 pipelined split-MFMA GEMM step macros (k_gemm_qkv / k_gemm_out).
// Wave grid 2x2; wave-tile 64m x 32n; acc[4][2]; B buf = 2048 shorts.
// ---------------------------------------------------------------------------
#define COMPUTE_TILE(SA, SB)                                                  \
  {                                                                           \
    const unsigned short* Ah_ = Abh + (SA) * 4096;                            \
    const unsigned short* Al_ = Abl + (SA) * 4096;                            \
    const unsigned short* Bh_ = Bbh + (SB) * 2048;                            \
    const unsigned short* Bl_ = Bbl + (SB) * 2048;                            \
    short8 ah_[4], al_[4], bh_[2], bl_[2];                                    \
    _Pragma("unroll") for (int i_ = 0; i_ < 4; i_++) {                        \
      int off_ = (mrbase + i_ * 16) * 32 + phA;                               \
      ah_[i_] = *(const short8*)(Ah_ + off_);                                 \
      al_[i_] = *(const short8*)(Al_ + off_);                                 \
    }                                                                         \
    _Pragma("unroll") for (int j_ = 0; j_ < 2; j_++) {                        \
      int off_ = q * 512 + (wc * 32 + j_ * 16 + lm) * 8;                      \
      bh_[j_] = *(const short8*)(Bh_ + off_);                                 \
      bl_[j_] = *(const short8*)(Bl_ + off_);                                 \
    }                                                                         \
    __builtin_amdgcn_s_setprio(1);                                            \
    _Pragma("unroll") for (int i_ = 0; i_ < 4; i_++)                          \
      _Pragma("unroll") for (int j_ = 0; j_ < 2; j_++) {                      \
        acc[i_][j_] = MFMA16(ah_[i_], bh_[j_], acc[i_][j_]);                  \
        acc[i_][j_] = MFMA16(ah_[i_], bl_[j_], acc[i_][j_]);                  \
        acc[i_][j_] = MFMA16(al_[i_], bh_[j_], acc[i_][j_]);                  \
      }                                                                       \
    __builtin_amdgcn_s_setprio(0);                                            \
  }

#define SPLIT_B(SB, S0x, S1x)                                                 \
  {                                                                           \
    unsigned short* BhN_ = Bbh + (SB) * 2048;                                 \
    unsigned short* BlN_ = Bbl + (SB) * 2048;                                 \
    float xs_[8] = {S0x.x, S0x.y, S0x.z, S0x.w,                               \
                    S1x.x, S1x.y, S1x.z, S1x.w};                              \
    short8 h_, l_;                                                            \
    split8v(xs_, h_, l_);                                                     \
    *(short8*)(BhN_ + c8 * 512 + rowB * 8) = h_;                              \
    *(short8*)(BlN_ + c8 * 512 + rowB * 8) = l_;                              \
  }

#define GSTEP(T, SCUR, S0x, S1x, L0x, L1x)                                    \
  {                                                                           \
    const int t_ = (T), sc_ = (SCUR);                                         \
    const int sn_ = sc_ >= 1 ? sc_ - 1 : 2; /* (sc_+2)%3 */                   \
    size_t tn_ = tb + (size_t)(t_ + 2) * 4096;                                \
    async_cp16(XH_ + tn_ + sidx0 * 8, Abh + sn_ * 4096 + sidx0 * 8);          \
    async_cp16(XL_ + tn_ + sidx0 * 8, Abl + sn_ * 4096 + sidx0 * 8);          \
    async_cp16(XH_ + tn_ + sidx1 * 8, Abh + sn_ * 4096 + sidx1 * 8);          \
    async_cp16(XL_ + tn_ + sidx1 * 8, Abl + sn_ * 4096 + sidx1 * 8);          \
    {                                                                         \
      int kn_ = (t_ + 2) * 32;                                                \
      L0x = *(const float4*)(pB0 + kn_);                                      \
      L1x = *(const float4*)(pB0 + kn_ + 4);                                  \
    }                                                                         \
    COMPUTE_TILE(sc_, (t_) & 1);                                              \
    SPLIT_B((t_ + 1) & 1, S0x, S1x);                                          \
    asm volatile("s_waitcnt vmcnt(6) lgkmcnt(0)" ::: "memory");               \
    __builtin_amdgcn_s_barrier();                                             \
    __builtin_amdgcn_sched_barrier(0);                                        \
  }

#define GEMM_PRO()                                                            \
  wB0 = *(const float4*)(pB0);                                                \
  wB1 = *(const float4*)(pB0 + 4);                                            \
  async_cp16(XH_ + tb + sidx0 * 8, Abh + sidx0 * 8);                          \
  async_cp16(XL_ + tb + sidx0 * 8, Abl + sidx0 * 8);                          \
  async_cp16(XH_ + tb + sidx1 * 8, Abh + sidx1 * 8);                          \
  async_cp16(XL_ + tb + sidx1 * 8, Abl + sidx1 * 8);                          \
  async_cp16(XH_ + tb + 4096 + sidx0 * 8, Abh + 4096 + sidx0 * 8);            \
  async_cp16(XL_ + tb + 4096 + sidx0 * 8, Abl + 4096 + sidx0 * 8);            \
  async_cp16(XH_ + tb + 4096 + sidx1 * 8, Abh + 4096 + sidx1 * 8);            \
  async_cp16(XL_ + tb + 4096 + sidx1 * 8, Abl + 4096 + sidx1 * 8);            \
  wA0 = *(const float4*)(pB0 + 32);                                           \
  wA1 = *(const float4*)(pB0 + 36);                                           \
  SPLIT_B(0, wB0, wB1);                                                       \
  asm volatile("s_waitcnt vmcnt(6) lgkmcnt(0)" ::: "memory");                 \
  __builtin_amdgcn_s_barrier();                                               \
  __builtin_amdgcn_sched_barrier(0);

#define GEMM_LOOP()                                                           \
  int scur = 0;                                                               \
  for (int p = 0; p < 23; ++p) {                                              \
    GSTEP(2 * p, scur, wA0, wA1, wB0, wB1);                                   \
    scur = (scur + 1 == 3) ? 0 : scur + 1;                                    \
    GSTEP(2 * p + 1, scur, wB0, wB1, wA0, wA1);                               \
    scur = (scur + 1 == 3) ? 0 : scur + 1;                                    \
  }                                                                           \
  /* t=46: A slot 1, B buf 0; split W(47) (in wA) -> buf 1. */                \
  COMPUTE_TILE(1, 0);                                                         \
  SPLIT_B(1, wA0, wA1);                                                       \
  asm volatile("s_waitcnt vmcnt(0) lgkmcnt(0)" ::: "memory");                 \
  __builtin_amdgcn_s_barrier();                                               \
  __builtin_amdgcn_sched_barrier(0);                                          \
  /* t=47: A slot 2, B buf 1. */                                              \
  COMPUTE_TILE(2, 1);

// ---------------------------------------------------------------------------
// K1: QKV projections: C[m,n] = sum_c X[m,c]*W[n,c]. BM=128 BN=64 BK=32.
// Grid: 1152 blocks (8 XCD x 144), m fastest within an XCD chunk.
// ---------------------------------------------------------------------------
__global__ __launch_bounds__(256) void k_gemm_qkv(
    const unsigned short* __restrict__ Xh, const unsigned short* __restrict__ Xl,
    const float* __restrict__ Wq, const float* __restrict__ Wk,
    const float* __restrict__ Wv, float* __restrict__ qf,
    float* __restrict__ kf, float* __restrict__ vf,
    unsigned int* __restrict__ scal) {
  __shared__ __align__(16) unsigned short Ahs[3][4096], Als[3][4096];
  __shared__ __align__(16) unsigned short Bhs[2][2048], Bls[2][2048];
  int tid = threadIdx.x;
  int L = blockIdx.x;                       // 1152 = 8 x 144 (bijective)
  int L2 = (L & 7) * 144 + (L >> 3);
  int by2 = L2 & 15, rest = L2 >> 4;        // rest 0..71
  int z = rest / 24, bx2 = rest % 24;
  const float* W = (z == 0) ? Wq : (z == 1) ? Wk : Wv;
  float* C = (z == 0) ? qf : (z == 1) ? kf : vf;
  int n0 = bx2 * 64, m0 = by2 * 128;
  int lane = tid & 63, w = tid >> 6;
  int wr = w >> 1, wc = w & 1, lm = lane & 15, q = lane >> 4;

  floatx4 acc[4][2];
#pragma unroll
  for (int i = 0; i < 4; i++)
#pragma unroll
    for (int j = 0; j < 2; j++) acc[i][j] = (floatx4){0.f, 0.f, 0.f, 0.f};

  int rowB = tid >> 2, c8 = tid & 3;
  const float* pB0 = W + (size_t)(n0 + rowB) * DIM + c8 * 8;
  size_t tb = (size_t)by2 * 48 * 4096;
  int sidx0 = tid, sidx1 = 256 + tid;
  int phA = (q ^ ((lm >> 1) & 3)) * 8;
  int mrbase = wr * 64 + lm;
  unsigned short* Abh = &Ahs[0][0];
  unsigned short* Abl = &Als[0][0];
  unsigned short* Bbh = &Bhs[0][0];
  unsigned short* Bbl = &Bls[0][0];
  const unsigned short* XH_ = Xh;
  const unsigned short* XL_ = Xl;
  float4 wA0, wA1, wB0, wB1;

  GEMM_PRO();
  GEMM_LOOP();

  float am = 0.f;
#pragma unroll
  for (int i = 0; i < 4; i++) {
    int row = m0 + wr * 64 + i * 16 + q * 4;
#pragma unroll
    for (int j = 0; j < 2; j++) {
      int col = n0 + wc * 32 + j * 16 + lm;
#pragma unroll
      for (int r = 0; r < 4; r++) {
        float v = acc[i][j][r];
        C[(size_t)(row + r) * DIM + col] = v;
        am = fmaxf(am, fabsf(v));
      }
    }
  }
#pragma unroll
  for (int mk = 32; mk >= 1; mk >>= 1) am = fmaxf(am, __shfl_xor(am, mk, 64));
  if (lane == 0) atomicMax(&scal[z], __float_as_uint(am));
}

// ---------------------------------------------------------------------------
// K2a: quantize + transpose V -> nvT[h][d][k] (bf16 integer values).
// ---------------------------------------------------------------------------
__global__ __launch_bounds__(256) void k_quant_vT(
    const float* __restrict__ vf, const unsigned int* __restrict__ scal,
    unsigned short* __restrict__ nvT) {
  __shared__ float T[64 * 65];
  int h = blockIdx.z, d0 = blockIdx.y * 64, k0 = blockIdx.x * 64;
  float s = __uint_as_float(scal[2]) / 127.f;
  int t = threadIdx.x;
#pragma unroll
  for (int i = 0; i < 16; i++) {
    int idx = i * 256 + t;
    int r = idx >> 6, c = idx & 63;
    float v = vf[(size_t)(k0 + r) * DIM + h * HD + d0 + c];
    T[r * 65 + c] = fminf(fmaxf(rintf(v / s), -128.f), 127.f);
  }
  __syncthreads();
#pragma unroll
  for (int i = 0; i < 16; i++) {
    int idx = i * 256 + t;
    int d = idx >> 6, r = idx & 63;
    nvT[(size_t)(h * HD + d0 + d) * SEQ + k0 + r] = f2bf(T[r * 65 + d]);
  }
}

// ---------------------------------------------------------------------------
// K2b: quantize q,k -> integer-valued bf16.
// ---------------------------------------------------------------------------
__global__ __launch_bounds__(256) void k_quant_qk(
    const float* __restrict__ qf, const float* __restrict__ kf,
    const unsigned int* __restrict__ scal,
    unsigned short* __restrict__ nq, unsigned short* __restrict__ nk) {
  int z = blockIdx.y;
  const float* src = z ? kf : qf;
  unsigned short* dst = z ? nk : nq;
  float s = __uint_as_float(scal[z]) / 127.f;
  size_t i = ((size_t)blockIdx.x * 256 + threadIdx.x) * 4;
  float4 v = *(const float4*)(src + i);
  ushort4 o;
  o.x = f2bf(fminf(fmaxf(rintf(v.x / s), -128.f), 127.f));
  o.y = f2bf(fminf(fmaxf(rintf(v.y / s), -128.f), 127.f));
  o.z = f2bf(fminf(fmaxf(rintf(v.z / s), -128.f), 127.f));
  o.w = f2bf(fminf(fmaxf(rintf(v.w / s), -128.f), 127.f));
  *(ushort4*)(dst + i) = o;
}

// ---------------------------------------------------------------------------
// K3: partial softmax stats, split-K x8, online per-lane (m,z), swizzled Ks.
// Grid: (8*16, NH). pstats[h][row][chunk][2]. __expf throughout.
// ---------------------------------------------------------------------------
__global__ __launch_bounds__(256) void k_stats(
    const unsigned short* __restrict__ nq, const unsigned short* __restrict__ nk,
    const unsigned int* __restrict__ scal, float* __restrict__ pstats) {
  __shared__ unsigned short Ks[32 * 128];
  int h = blockIdx.y, tid = threadIdx.x, lane = tid & 63, w = tid >> 6;
  int lm = lane & 15, q = lane >> 4;
  int qb = blockIdx.x & 15, chunk = blockIdx.x >> 4;
  int mb = qb * 128 + w * 32;
  int kbase = chunk * 256;
  float f = (__uint_as_float(scal[0]) / 127.f) *
            (__uint_as_float(scal[1]) / 127.f) * SCALEF;

  short8 aq[2][4];
#pragma unroll
  for (int mi = 0; mi < 2; mi++) {
    const unsigned short* qb_p =
        nq + (size_t)(mb + mi * 16 + lm) * DIM + h * HD + q * 8;
#pragma unroll
    for (int cc = 0; cc < 4; cc++) aq[mi][cc] = *(const short8*)(qb_p + cc * 32);
  }

  float m[2][4], zz[2][4];
#pragma unroll
  for (int mi = 0; mi < 2; mi++)
#pragma unroll
    for (int r = 0; r < 4; r++) { m[mi][r] = -3.0e38f; zz[mi][r] = 0.f; }

  for (int kt = kbase; kt < kbase + 256; kt += 32) {
    __syncthreads();
#pragma unroll
    for (int i = 0; i < 2; i++) {
      int ch = i * 256 + tid;
      int krow = ch >> 4;
      int gcol = (ch & 15) ^ (krow & 7);  // xor-swizzle source column
      async_cp16(nk + (size_t)(kt + krow) * DIM + h * HD + gcol * 8,
                 Ks + ch * 8);
    }
    __syncthreads();
    short8 bk[2][4];
#pragma unroll
    for (int st = 0; st < 2; st++)
#pragma unroll
      for (int cc = 0; cc < 4; cc++) {
        int phys = (cc * 4 + q) ^ (lm & 7);
        bk[st][cc] = *(const short8*)(Ks + (st * 16 + lm) * 128 + phys * 8);
      }
#pragma unroll
    for (int mi = 0; mi < 2; mi++) {
      floatx4 a0 = (floatx4){0.f, 0.f, 0.f, 0.f};
      floatx4 a1 = (floatx4){0.f, 0.f, 0.f, 0.f};
#pragma unroll
      for (int cc = 0; cc < 4; cc++) {
        a0 = MFMA16(aq[mi][cc], bk[0][cc], a0);
        a1 = MFMA16(aq[mi][cc], bk[1][cc], a1);
      }
#pragma unroll
      for (int r = 0; r < 4; r++) {
        float s0 = a0[r] * f, s1 = a1[r] * f;
        float nm = fmaxf(m[mi][r], fmaxf(s0, s1));
        zz[mi][r] = zz[mi][r] * __expf(m[mi][r] - nm) + __expf(s0 - nm) +
                    __expf(s1 - nm);
        m[mi][r] = nm;
      }
    }
  }
  // merge (m,z) across the 16 lanes sharing each row
#pragma unroll
  for (int mk = 1; mk < 16; mk <<= 1)
#pragma unroll
    for (int mi = 0; mi < 2; mi++)
#pragma unroll
      for (int r = 0; r < 4; r++) {
        float om = __shfl_xor(m[mi][r], mk, 64);
        float oz = __shfl_xor(zz[mi][r], mk, 64);
        float nm = fmaxf(m[mi][r], om);
        zz[mi][r] = zz[mi][r] * __expf(m[mi][r] - nm) + oz * __expf(om - nm);
        m[mi][r] = nm;
      }
  if (lm == 0) {
#pragma unroll
    for (int mi = 0; mi < 2; mi++)
#pragma unroll
      for (int r = 0; r < 4; r++) {
        int row = mb + mi * 16 + q * 4 + r;
        float* p = pstats + (((size_t)h * SEQ + row) * 8 + chunk) * 2;
        p[0] = m[mi][r];
        p[1] = zz[mi][r];
      }
  }
}

// ---------------------------------------------------------------------------
// K3b: merge 8 partial stats per row -> stats[h][row][2], global minZ.
// ---------------------------------------------------------------------------
__global__ __launch_bounds__(256) void k_merge(
    const float* __restrict__ pstats, float* __restrict__ stats,
    unsigned int* __restrict__ minZ) {
  int idx = blockIdx.x * 256 + threadIdx.x;  // h*SEQ + row
  const float* p = pstats + (size_t)idx * 16;
  float M = -3.0e38f;
#pragma unroll
  for (int c = 0; c < 8; c++) M = fmaxf(M, p[c * 2]);
  float Z = 0.f;
#pragma unroll
  for (int c = 0; c < 8; c++) Z += p[c * 2 + 1] * __expf(p[c * 2] - M);
  stats[(size_t)idx * 2] = M;
  stats[(size_t)idx * 2 + 1] = Z;
  atomicMin(minZ, __float_as_uint(Z));
}

// ---------------------------------------------------------------------------
// K4: pass 2 — scores, quantize probs, PV. Split-K x2 -> partial O buffers.
// Grid: (2*16, NH). Swizzled Ks and Vs. __expf throughout.
// ---------------------------------------------------------------------------
__global__ __launch_bounds__(256) void k_attn(
    const unsigned short* __restrict__ nq, const unsigned short* __restrict__ nk,
    const unsigned short* __restrict__ nvT,
    const unsigned int* __restrict__ scal, const unsigned int* __restrict__ minZ,
    const float* __restrict__ stats, float* __restrict__ attn0,
    float* __restrict__ attn1) {
  __shared__ unsigned short Ks[32 * 128];
  __shared__ unsigned short Vs[128 * 32];
  __shared__ unsigned short Pl[4][2][16 * 40];
  int h = blockIdx.y, tid = threadIdx.x, lane = tid & 63, w = tid >> 6;
  int lm = lane & 15, q = lane >> 4;
  int qb = blockIdx.x & 15, chunk = blockIdx.x >> 4;
  int mb = qb * 128 + w * 32;
  float* attn = chunk ? attn1 : attn0;
  float sv = __uint_as_float(scal[2]) / 127.f;
  float f = (__uint_as_float(scal[0]) / 127.f) *
            (__uint_as_float(scal[1]) / 127.f) * SCALEF;
  float sp = (1.f / __uint_as_float(*minZ)) / 127.f;
  float inv_sp = 1.f / sp;

  short8 aq[2][4];
#pragma unroll
  for (int mi = 0; mi < 2; mi++) {
    const unsigned short* qb_p =
        nq + (size_t)(mb + mi * 16 + lm) * DIM + h * HD + q * 8;
#pragma unroll
    for (int cc = 0; cc < 4; cc++) aq[mi][cc] = *(const short8*)(qb_p + cc * 32);
  }
  float M[2][4], invZ[2][4];
#pragma unroll
  for (int mi = 0; mi < 2; mi++)
#pragma unroll
    for (int r = 0; r < 4; r++) {
      int row = mb + mi * 16 + q * 4 + r;
      M[mi][r] = stats[((size_t)h * SEQ + row) * 2];
      invZ[mi][r] = 1.f / stats[((size_t)h * SEQ + row) * 2 + 1];
    }
  floatx4 accO[2][8];
#pragma unroll
  for (int mi = 0; mi < 2; mi++)
#pragma unroll
    for (int j = 0; j < 8; j++) accO[mi][j] = (floatx4){0.f, 0.f, 0.f, 0.f};

  int kbase = chunk * 1024;
  for (int kt = kbase; kt < kbase + 1024; kt += 32) {
    __syncthreads();
#pragma unroll
    for (int i = 0; i < 2; i++) {
      int ch = i * 256 + tid;
      int krow = ch >> 4;
      int gcol = (ch & 15) ^ (krow & 7);
      async_cp16(nk + (size_t)(kt + krow) * DIM + h * HD + gcol * 8,
                 Ks + ch * 8);
      int d = ch >> 2;
      int vcol = (ch & 3) ^ ((d >> 1) & 3);
      async_cp16(nvT + (size_t)(h * HD + d) * SEQ + kt + vcol * 8,
                 Vs + ch * 8);
    }
    __syncthreads();
    short8 bk[2][4];
#pragma unroll
    for (int st = 0; st < 2; st++)
#pragma unroll
      for (int cc = 0; cc < 4; cc++) {
        int phys = (cc * 4 + q) ^ (lm & 7);
        bk[st][cc] = *(const short8*)(Ks + (st * 16 + lm) * 128 + phys * 8);
      }
#pragma unroll
    for (int mi = 0; mi < 2; mi++)
#pragma unroll
      for (int st = 0; st < 2; st++) {
        floatx4 acc = (floatx4){0.f, 0.f, 0.f, 0.f};
#pragma unroll
        for (int cc = 0; cc < 4; cc++) acc = MFMA16(aq[mi][cc], bk[st][cc], acc);
#pragma unroll
        for (int r = 0; r < 4; r++) {
          float t = __expf(acc[r] * f - M[mi][r]);
          float n = rintf(t * invZ[mi][r] * inv_sp);
          n = fminf(n, 127.f);
          Pl[w][mi][(q * 4 + r) * 40 + st * 16 + lm] = f2bf(n);
        }
      }
    __syncthreads();
    short8 ap[2];
#pragma unroll
    for (int mi = 0; mi < 2; mi++)
      ap[mi] = *(const short8*)(&Pl[w][mi][lm * 40 + q * 8]);
#pragma unroll
    for (int j = 0; j < 8; j++) {
      int d = j * 16 + lm;
      int vphys = q ^ ((d >> 1) & 3);
      short8 bv = *(const short8*)(Vs + d * 32 + vphys * 8);
#pragma unroll
      for (int mi = 0; mi < 2; mi++) accO[mi][j] = MFMA16(ap[mi], bv, accO[mi][j]);
    }
  }
  float osc = sp * sv;
#pragma unroll
  for (int mi = 0; mi < 2; mi++)
#pragma unroll
    for (int j = 0; j < 8; j++)
#pragma unroll
      for (int r = 0; r < 4; r++)
        attn[(size_t)(mb + mi * 16 + q * 4 + r) * DIM + h * HD + j * 16 + lm] =
            accO[mi][j][r] * osc;
}

// ---------------------------------------------------------------------------
// K5: out-proj: out[m,n] = sum_c O[m,c]*Wo[n,c] + bo[n]. BM=128 BN=64.
// Grid: 384 blocks (8 XCD x 48).
// ---------------------------------------------------------------------------
__global__ __launch_bounds__(256) void k_gemm_out(
    const unsigned short* __restrict__ Oh, const unsigned short* __restrict__ Ol,
    const float* __restrict__ Wo, const float* __restrict__ bo,
    float* __restrict__ out) {
  __shared__ __align__(16) unsigned short Ahs[3][4096], Als[3][4096];
  __shared__ __align__(16) unsigned short Bhs[2][2048], Bls[2][2048];
  int tid = threadIdx.x;
  int L = blockIdx.x;                       // 384 = 8 x 48 (bijective)
  int L2 = (L & 7) * 48 + (L >> 3);
  int by2 = L2 & 15, bx2 = L2 >> 4;         // bx2 0..23
  int n0 = bx2 * 64, m0 = by2 * 128;
  int lane = tid & 63, w = tid >> 6;
  int wr = w >> 1, wc = w & 1, lm = lane & 15, q = lane >> 4;

  floatx4 acc[4][2];
#pragma unroll
  for (int i = 0; i < 4; i++)
#pragma unroll
    for (int j = 0; j < 2; j++) acc[i][j] = (floatx4){0.f, 0.f, 0.f, 0.f};

  int rowB = tid >> 2, c8 = tid & 3;
  const float* pB0 = Wo + (size_t)(n0 + rowB) * DIM + c8 * 8;
  size_t tb = (size_t)by2 * 48 * 4096;
  int sidx0 = tid, sidx1 = 256 + tid;
  int phA = (q ^ ((lm >> 1) & 3)) * 8;
  int mrbase = wr * 64 + lm;
  unsigned short* Abh = &Ahs[0][0];
  unsigned short* Abl = &Als[0][0];
  unsigned short* Bbh = &Bhs[0][0];
  unsigned short* Bbl = &Bls[0][0];
  const unsigned short* XH_ = Oh;
  const unsigned short* XL_ = Ol;
  float4 wA0, wA1, wB0, wB1;

  GEMM_PRO();
  GEMM_LOOP();

#pragma unroll
  for (int j = 0; j < 2; j++) {
    int col = n0 + wc * 32 + j * 16 + lm;
    float bias = bo[col];
#pragma unroll
    for (int i = 0; i < 4; i++) {
      int row = m0 + wr * 64 + i * 16 + q * 4;
#pragma unroll
      for (int r = 0; r < 4; r++)
        out[(size_t)(row + r) * DIM + col] = acc[i][j][r] + bias;
    }
  }
}

// ---------------------------------------------------------------------------
extern "C" void kernel_launch(void* const* d_in, const int* in_sizes, int n_in,
                              void* d_out, int out_size, void* d_ws, size_t ws_size,
                              hipStream_t stream) {
  float* out = (float*)d_out;
  bool sizes_ok = (n_in >= 6) && in_sizes && in_sizes[0] == SEQ * DIM &&
                  in_sizes[1] == DIM * DIM && in_sizes[2] == DIM * DIM &&
                  in_sizes[3] == DIM * DIM && in_sizes[4] == DIM * DIM &&
                  in_sizes[5] == DIM && out_size == SEQ * DIM;
  if (!sizes_ok) {
    k_fill<<<(out_size + 255) / 256, 256, 0, stream>>>(out, out_size, 1.0f);
    return;
  }
  if (ws_size < 50528272) {
    k_fill<<<(out_size + 255) / 256, 256, 0, stream>>>(out, out_size, 2.0f);
    return;
  }

  const float* x  = (const float*)d_in[0];
  const float* Wq = (const float*)d_in[1];
  const float* Wk = (const float*)d_in[2];
  const float* Wv = (const float*)d_in[3];
  const float* Wo = (const float*)d_in[4];
  const float* bo = (const float*)d_in[5];
  char* ws = (char*)d_ws;

  // Workspace layout (peak < 50.53 MB):
  float* qf = (float*)(ws);                                // 12,582,912 B
  float* kf = (float*)(ws + 12582912);                     // 12,582,912 B
  float* vf = (float*)(ws + 25165824);                     // 12,582,912 B
  unsigned short* nq  = (unsigned short*)(ws + 25165824);  // aliases vf (dead)
  float* pstats = (float*)(ws + 31457280);                 // 1,572,864 B
  unsigned short* nvT = (unsigned short*)(ws + 37748736);  // 6,291,456 B
  unsigned short* nk  = (unsigned short*)(ws + 44040192);  // 6,291,456 B
  // X-split tiled planes live in the nvT/nk slots until quant kernels run:
  unsigned short* Xh = nvT;   // dead after k_gemm_qkv
  unsigned short* Xl = nk;    // dead after k_gemm_qkv
  // attn-output tiled planes reuse the same slots after k_attn:
  unsigned short* Oh = nvT;   // written by k_split_o (nvT dead after k_attn)
  unsigned short* Ol = nk;    // written by k_split_o (nk dead after k_attn)
  float* attn0 = qf;                                       // aliases qf (dead)
  float* attn1 = kf;                                       // aliases kf (dead)
  float* stats = (float*)(ws + 50331648);                  // 196,608 B
  unsigned int* scal = (unsigned int*)(ws + 50528256);     // 16 B

  hipMemsetAsync(scal, 0, 12, stream);
  hipMemsetAsync(scal + 3, 0x7f, 4, stream);  // minZ init ~3.39e38

  k_split_x<<<dim3(48, 16), 256, 0, stream>>>(x, Xh, Xl);
  k_gemm_qkv<<<dim3(1152), 256, 0, stream>>>(Xh, Xl, Wq, Wk, Wv, qf, kf, vf,
                                             scal);
  k_quant_vT<<<dim3(SEQ / 64, HD / 64, NH), 256, 0, stream>>>(vf, scal, nvT);
  k_quant_qk<<<dim3((SEQ * DIM) / 1024, 2), 256, 0, stream>>>(qf, kf, scal, nq, nk);
  k_stats<<<dim3(8 * 16, NH), 256, 0, stream>>>(nq, nk, scal, pstats);
  k_merge<<<dim3(NH * SEQ / 256), 256, 0, stream>>>(pstats, stats, scal + 3);
  k_attn<<<dim3(2 * 16, NH), 256, 0, stream>>>(nq, nk, nvT, scal, scal + 3,
                                               stats, attn0, attn1);
  k_split_o<<<dim3(48, 16), 256, 0, stream>>>(attn0, attn1, Oh, Ol);
  k_gemm_out<<<dim3(384), 256, 0, stream>>>(Oh, Ol, Wo, bo, out);
}

// Round 11
// 464.614 us; speedup vs baseline: 1.0499x; 1.0499x over previous
//
#include <hip/hip_runtime.h>
#include <stdint.h>

// B=1, L=2048, DIM=1536, H=12, HD=128. Inputs f32, output f32 (verified R6).
// R16: __expf in softmax path => 523->472.8us (best), absmax bit-identical.
// R17/R18: BN=64 GEMMs FALSIFIED the TLP theory: qkv 195->244us, FETCH
// 90->161MB (A re-read by 2x n-blocks, not cache-absorbed). 7th qkv
// experiment => frozen at the R16 form (~195us invariant wall for this
// decomposition).
// R19: GEMMs reverted to R16-exact. k_attn granularity: 16 rows/wave (drop
// mi), grid (2*32,NH)=768 blocks => 3 waves/SIMD (was 1.5) for the staging-
// latency-bound 2-phase loop. Per-row math order unchanged => bit-identical.
#define SEQ 2048
#define DIM 1536
#define NH  12
#define HD  128
#define SCALEF 0.08838834764831845f  // 128^-0.5

typedef __attribute__((ext_vector_type(8))) short short8;
typedef __attribute__((ext_vector_type(4))) float floatx4;

#define MFMA16(a, b, c) __builtin_amdgcn_mfma_f32_16x16x32_bf16((a), (b), (c), 0, 0, 0)

__device__ __forceinline__ void async_cp16(const void* g, void* l) {
  __builtin_amdgcn_global_load_lds(
      (__attribute__((address_space(1))) unsigned int*)(g),
      (__attribute__((address_space(3))) unsigned int*)(l), 16, 0, 0);
}

__device__ __forceinline__ unsigned short f2bf(float f) {
  unsigned int u = __float_as_uint(f);
  u = (u + 0x7fff + ((u >> 16) & 1)) >> 16;  // RNE
  return (unsigned short)u;
}

// Split f32 -> hi (truncated bf16) + lo (RNE bf16 of residual).
__device__ __forceinline__ void split8v(const float* x, short8& h, short8& l) {
#pragma unroll
  for (int e = 0; e < 8; e++) {
    unsigned int u = __float_as_uint(x[e]);
    h[e] = (short)(u >> 16);
    float r = x[e] - __uint_as_float(u & 0xFFFF0000u);
    l[e] = (short)f2bf(r);
  }
}
__device__ __forceinline__ void split8(const float* g, short8& h, short8& l) {
  float4 f0 = *(const float4*)g, f1 = *(const float4*)(g + 4);
  float x[8] = {f0.x, f0.y, f0.z, f0.w, f1.x, f1.y, f1.z, f1.w};
  split8v(x, h, l);
}

__global__ __launch_bounds__(256) void k_fill(float* __restrict__ out, int n,
                                              float val) {
  int i = blockIdx.x * 256 + threadIdx.x;
  if (i < n) out[i] = val;
}

// ---------------------------------------------------------------------------
// K0a: pre-split X -> tiled bf16 planes. Tile (mb,ks) = 8KB contiguous,
// rows mb*128..+127 x k ks*32..+31, chunk-xor (p ^ (row>>1)&3) pre-applied.
// Grid: (48 ks, 16 mb).
// ---------------------------------------------------------------------------
__global__ __launch_bounds__(256) void k_split_x(
    const float* __restrict__ X, unsigned short* __restrict__ Xh,
    unsigned short* __restrict__ Xl) {
  int ks = blockIdx.x, mb = blockIdx.y, tid = threadIdx.x;
  size_t tb = ((size_t)mb * 48 + ks) * 4096;
#pragma unroll
  for (int i = 0; i < 2; i++) {
    int sidx = i * 256 + tid;
    int row = sidx >> 2, p = sidx & 3;
    int c = p ^ ((row >> 1) & 3);
    short8 h, l;
    split8(X + (size_t)(mb * 128 + row) * DIM + ks * 32 + c * 8, h, l);
    *(short8*)(Xh + tb + sidx * 8) = h;
    *(short8*)(Xl + tb + sidx * 8) = l;
  }
}

// ---------------------------------------------------------------------------
// K0b: pre-sum + split attn output -> tiled Oh/Ol (same layout as k_split_x).
// ---------------------------------------------------------------------------
__global__ __launch_bounds__(256) void k_split_o(
    const float* __restrict__ A0, const float* __restrict__ A1,
    unsigned short* __restrict__ Oh, unsigned short* __restrict__ Ol) {
  int ks = blockIdx.x, mb = blockIdx.y, tid = threadIdx.x;
  size_t tb = ((size_t)mb * 48 + ks) * 4096;
#pragma unroll
  for (int i = 0; i < 2; i++) {
    int sidx = i * 256 + tid;
    int row = sidx >> 2, p = sidx & 3;
    int c = p ^ ((row >> 1) & 3);
    size_t off = (size_t)(mb * 128 + row) * DIM + ks * 32 + c * 8;
    float4 x0 = *(const float4*)(A0 + off), x1 = *(const float4*)(A0 + off + 4);
    float4 y0 = *(const float4*)(A1 + off), y1 = *(const float4*)(A1 + off + 4);
    float xs[8] = {x0.x + y0.x, x0.y + y0.y, x0.z + y0.z, x0.w + y0.w,
                   x1.x + y1.x, x1.y + y1.y, x1.z + y1.z, x1.w + y1.w};
    short8 h, l;
    split8v(xs, h, l);
    *(short8*)(Oh + tb + sidx * 8) = h;
    *(short8*)(Ol + tb + sidx * 8) = l;
  }
}

// ---------------------------------------------------------------------------
// Pipelined split-MFMA GEMM step macros (shared by k_gemm_qkv / k_gemm_out).
// ---------------------------------------------------------------------------
#define COMPUTE_TILE(SA, SB)                                                  \
  {                                                                           \
    const unsigned short* Ah_ = Abh + (SA) * 4096;                            \
    const unsigned short* Al_ = Abl + (SA) * 4096;                            \
    const unsigned short* Bh_ = Bbh + (SB) * 4096;                            \
    const unsigned short* Bl_ = Bbl + (SB) * 4096;                            \
    short8 ah_[4], al_[4], bh_[4], bl_[4];                                    \
    _Pragma("unroll") for (int i_ = 0; i_ < 4; i_++) {                        \
      int off_ = (mrbase + i_ * 16) * 32 + phA;                               \
      ah_[i_] = *(const short8*)(Ah_ + off_);                                 \
      al_[i_] = *(const short8*)(Al_ + off_);                                 \
    }                                                                         \
    _Pragma("unroll") for (int j_ = 0; j_ < 4; j_++) {                        \
      int off_ = q * 1024 + (wc * 64 + j_ * 16 + lm) * 8;                     \
      bh_[j_] = *(const short8*)(Bh_ + off_);                                 \
      bl_[j_] = *(const short8*)(Bl_ + off_);                                 \
    }                                                                         \
    __builtin_amdgcn_s_setprio(1);                                            \
    _Pragma("unroll") for (int i_ = 0; i_ < 4; i_++)                          \
      _Pragma("unroll") for (int j_ = 0; j_ < 4; j_++) {                      \
        acc[i_][j_] = MFMA16(ah_[i_], bh_[j_], acc[i_][j_]);                  \
        acc[i_][j_] = MFMA16(ah_[i_], bl_[j_], acc[i_][j_]);                  \
        acc[i_][j_] = MFMA16(al_[i_], bh_[j_], acc[i_][j_]);                  \
      }                                                                       \
    __builtin_amdgcn_s_setprio(0);                                            \
  }

#define SPLIT_B(SB, S0x, S1x, S2x, S3x)                                       \
  {                                                                           \
    unsigned short* BhN_ = Bbh + (SB) * 4096;                                 \
    unsigned short* BlN_ = Bbl + (SB) * 4096;                                 \
    short8 h_, l_;                                                            \
    {                                                                         \
      float xs_[8] = {S0x.x, S0x.y, S0x.z, S0x.w,                             \
                      S1x.x, S1x.y, S1x.z, S1x.w};                            \
      split8v(xs_, h_, l_);                                                   \
      *(short8*)(BhN_ + c8 * 1024 + rowA * 8) = h_;                           \
      *(short8*)(BlN_ + c8 * 1024 + rowA * 8) = l_;                           \
    }                                                                         \
    {                                                                         \
      float xs_[8] = {S2x.x, S2x.y, S2x.z, S2x.w,                             \
                      S3x.x, S3x.y, S3x.z, S3x.w};                            \
      split8v(xs_, h_, l_);                                                   \
      *(short8*)(BhN_ + c8 * 1024 + (64 + rowA) * 8) = h_;                    \
      *(short8*)(BlN_ + c8 * 1024 + (64 + rowA) * 8) = l_;                    \
    }                                                                         \
  }

#define GSTEP(T, SCUR, S0x, S1x, S2x, S3x, L0x, L1x, L2x, L3x)                \
  {                                                                           \
    const int t_ = (T), sc_ = (SCUR);                                         \
    const int sn_ = sc_ >= 1 ? sc_ - 1 : 2; /* (sc_+2)%3 */                   \
    size_t tn_ = tb + (size_t)(t_ + 2) * 4096;                                \
    async_cp16(XH_ + tn_ + sidx0 * 8, Abh + sn_ * 4096 + sidx0 * 8);          \
    async_cp16(XL_ + tn_ + sidx0 * 8, Abl + sn_ * 4096 + sidx0 * 8);          \
    async_cp16(XH_ + tn_ + sidx1 * 8, Abh + sn_ * 4096 + sidx1 * 8);          \
    async_cp16(XL_ + tn_ + sidx1 * 8, Abl + sn_ * 4096 + sidx1 * 8);          \
    {                                                                         \
      int kn_ = (t_ + 2) * 32;                                                \
      L0x = *(const float4*)(pB0 + kn_);                                      \
      L1x = *(const float4*)(pB0 + kn_ + 4);                                  \
      L2x = *(const float4*)(pB1 + kn_);                                      \
      L3x = *(const float4*)(pB1 + kn_ + 4);                                  \
    }                                                                         \
    COMPUTE_TILE(sc_, (t_) & 1);                                              \
    SPLIT_B((t_ + 1) & 1, S0x, S1x, S2x, S3x);                                \
    asm volatile("s_waitcnt vmcnt(8) lgkmcnt(0)" ::: "memory");               \
    __builtin_amdgcn_s_barrier();                                             \
    __builtin_amdgcn_sched_barrier(0);                                        \
  }

// ---------------------------------------------------------------------------
// K1: QKV projections: C[m,n] = sum_c X[m,c]*W[n,c]. Split-MFMA, 128x128
// tile, 3-deep A pipeline + W double-reg + counted vmcnt. Grid: (12,16,3).
// ---------------------------------------------------------------------------
__global__ __launch_bounds__(256) void k_gemm_qkv(
    const unsigned short* __restrict__ Xh, const unsigned short* __restrict__ Xl,
    const float* __restrict__ Wq, const float* __restrict__ Wk,
    const float* __restrict__ Wv, float* __restrict__ qf,
    float* __restrict__ kf, float* __restrict__ vf,
    unsigned int* __restrict__ scal) {
  __shared__ __align__(16) unsigned short Ahs[3][4096], Als[3][4096];
  __shared__ __align__(16) unsigned short Bhs[2][4096], Bls[2][4096];
  int tid = threadIdx.x;
  // bijective XCD swizzle: 576 blocks = 8 XCDs x 72.
  int L = blockIdx.x + 12 * blockIdx.y + 192 * blockIdx.z;
  int L2 = (L & 7) * 72 + (L >> 3);
  int by2 = L2 & 15, rest = L2 >> 4;
  int bx2 = rest % 12, z = rest / 12;
  const float* W = (z == 0) ? Wq : (z == 1) ? Wk : Wv;
  float* C = (z == 0) ? qf : (z == 1) ? kf : vf;
  int n0 = bx2 * 128, m0 = by2 * 128;
  int lane = tid & 63, w = tid >> 6;
  int wr = w >> 1, wc = w & 1, lm = lane & 15, q = lane >> 4;

  floatx4 acc[4][4];
#pragma unroll
  for (int i = 0; i < 4; i++)
#pragma unroll
    for (int j = 0; j < 4; j++) acc[i][j] = (floatx4){0.f, 0.f, 0.f, 0.f};

  int rowA = tid >> 2, c8 = tid & 3;
  const float* pB0 = W + (size_t)(n0 + rowA) * DIM + c8 * 8;
  const float* pB1 = pB0 + (size_t)64 * DIM;
  size_t tb = (size_t)by2 * 48 * 4096;
  int sidx0 = tid, sidx1 = 256 + tid;
  int phA = (q ^ ((lm >> 1) & 3)) * 8;
  int mrbase = wr * 64 + lm;
  unsigned short* Abh = &Ahs[0][0];
  unsigned short* Abl = &Als[0][0];
  unsigned short* Bbh = &Bhs[0][0];
  unsigned short* Bbl = &Bls[0][0];
  const unsigned short* XH_ = Xh;
  const unsigned short* XL_ = Xl;

  float4 wA0, wA1, wA2, wA3, wB0, wB1, wB2, wB3;
  // prologue: W(0) -> wB (split now), A(0)->slot0, A(1)->slot1, W(1) -> wA.
  wB0 = *(const float4*)(pB0);
  wB1 = *(const float4*)(pB0 + 4);
  wB2 = *(const float4*)(pB1);
  wB3 = *(const float4*)(pB1 + 4);
  async_cp16(XH_ + tb + sidx0 * 8, Abh + sidx0 * 8);
  async_cp16(XL_ + tb + sidx0 * 8, Abl + sidx0 * 8);
  async_cp16(XH_ + tb + sidx1 * 8, Abh + sidx1 * 8);
  async_cp16(XL_ + tb + sidx1 * 8, Abl + sidx1 * 8);
  async_cp16(XH_ + tb + 4096 + sidx0 * 8, Abh + 4096 + sidx0 * 8);
  async_cp16(XL_ + tb + 4096 + sidx0 * 8, Abl + 4096 + sidx0 * 8);
  async_cp16(XH_ + tb + 4096 + sidx1 * 8, Abh + 4096 + sidx1 * 8);
  async_cp16(XL_ + tb + 4096 + sidx1 * 8, Abl + 4096 + sidx1 * 8);
  wA0 = *(const float4*)(pB0 + 32);
  wA1 = *(const float4*)(pB0 + 36);
  wA2 = *(const float4*)(pB1 + 32);
  wA3 = *(const float4*)(pB1 + 36);
  SPLIT_B(0, wB0, wB1, wB2, wB3);
  asm volatile("s_waitcnt vmcnt(8) lgkmcnt(0)" ::: "memory");
  __builtin_amdgcn_s_barrier();
  __builtin_amdgcn_sched_barrier(0);

  int scur = 0;
  for (int p = 0; p < 23; ++p) {
    GSTEP(2 * p, scur, wA0, wA1, wA2, wA3, wB0, wB1, wB2, wB3);
    scur = (scur + 1 == 3) ? 0 : scur + 1;
    GSTEP(2 * p + 1, scur, wB0, wB1, wB2, wB3, wA0, wA1, wA2, wA3);
    scur = (scur + 1 == 3) ? 0 : scur + 1;
  }
  // t=46: A slot 1, B slot 0; split W(47) (in wA) -> B slot 1.
  COMPUTE_TILE(1, 0);
  SPLIT_B(1, wA0, wA1, wA2, wA3);
  asm volatile("s_waitcnt lgkmcnt(0)" ::: "memory");
  __builtin_amdgcn_s_barrier();
  __builtin_amdgcn_sched_barrier(0);
  // t=47: A slot 2, B slot 1.
  COMPUTE_TILE(2, 1);

  float am = 0.f;
#pragma unroll
  for (int i = 0; i < 4; i++) {
    int row = m0 + wr * 64 + i * 16 + q * 4;
#pragma unroll
    for (int j = 0; j < 4; j++) {
      int col = n0 + wc * 64 + j * 16 + lm;
#pragma unroll
      for (int r = 0; r < 4; r++) {
        float v = acc[i][j][r];
        C[(size_t)(row + r) * DIM + col] = v;
        am = fmaxf(am, fabsf(v));
      }
    }
  }
#pragma unroll
  for (int mk = 32; mk >= 1; mk >>= 1) am = fmaxf(am, __shfl_xor(am, mk, 64));
  if (lane == 0) atomicMax(&scal[z], __float_as_uint(am));
}

// ---------------------------------------------------------------------------
// K2a: quantize + transpose V -> nvT[h][d][k] (bf16 integer values).
// ---------------------------------------------------------------------------
__global__ __launch_bounds__(256) void k_quant_vT(
    const float* __restrict__ vf, const unsigned int* __restrict__ scal,
    unsigned short* __restrict__ nvT) {
  __shared__ float T[64 * 65];
  int h = blockIdx.z, d0 = blockIdx.y * 64, k0 = blockIdx.x * 64;
  float s = __uint_as_float(scal[2]) / 127.f;
  int t = threadIdx.x;
#pragma unroll
  for (int i = 0; i < 16; i++) {
    int idx = i * 256 + t;
    int r = idx >> 6, c = idx & 63;
    float v = vf[(size_t)(k0 + r) * DIM + h * HD + d0 + c];
    T[r * 65 + c] = fminf(fmaxf(rintf(v / s), -128.f), 127.f);
  }
  __syncthreads();
#pragma unroll
  for (int i = 0; i < 16; i++) {
    int idx = i * 256 + t;
    int d = idx >> 6, r = idx & 63;
    nvT[(size_t)(h * HD + d0 + d) * SEQ + k0 + r] = f2bf(T[r * 65 + d]);
  }
}

// ---------------------------------------------------------------------------
// K2b: quantize q,k -> integer-valued bf16.
// ---------------------------------------------------------------------------
__global__ __launch_bounds__(256) void k_quant_qk(
    const float* __restrict__ qf, const float* __restrict__ kf,
    const unsigned int* __restrict__ scal,
    unsigned short* __restrict__ nq, unsigned short* __restrict__ nk) {
  int z = blockIdx.y;
  const float* src = z ? kf : qf;
  unsigned short* dst = z ? nk : nq;
  float s = __uint_as_float(scal[z]) / 127.f;
  size_t i = ((size_t)blockIdx.x * 256 + threadIdx.x) * 4;
  float4 v = *(const float4*)(src + i);
  ushort4 o;
  o.x = f2bf(fminf(fmaxf(rintf(v.x / s), -128.f), 127.f));
  o.y = f2bf(fminf(fmaxf(rintf(v.y / s), -128.f), 127.f));
  o.z = f2bf(fminf(fmaxf(rintf(v.z / s), -128.f), 127.f));
  o.w = f2bf(fminf(fmaxf(rintf(v.w / s), -128.f), 127.f));
  *(ushort4*)(dst + i) = o;
}

// ---------------------------------------------------------------------------
// K3: partial softmax stats, split-K x8, online per-lane (m,z), swizzled Ks.
// Grid: (8*16, NH). pstats[h][row][chunk][2]. __expf throughout.
// ---------------------------------------------------------------------------
__global__ __launch_bounds__(256) void k_stats(
    const unsigned short* __restrict__ nq, const unsigned short* __restrict__ nk,
    const unsigned int* __restrict__ scal, float* __restrict__ pstats) {
  __shared__ unsigned short Ks[32 * 128];
  int h = blockIdx.y, tid = threadIdx.x, lane = tid & 63, w = tid >> 6;
  int lm = lane & 15, q = lane >> 4;
  int qb = blockIdx.x & 15, chunk = blockIdx.x >> 4;
  int mb = qb * 128 + w * 32;
  int kbase = chunk * 256;
  float f = (__uint_as_float(scal[0]) / 127.f) *
            (__uint_as_float(scal[1]) / 127.f) * SCALEF;

  short8 aq[2][4];
#pragma unroll
  for (int mi = 0; mi < 2; mi++) {
    const unsigned short* qb_p =
        nq + (size_t)(mb + mi * 16 + lm) * DIM + h * HD + q * 8;
#pragma unroll
    for (int cc = 0; cc < 4; cc++) aq[mi][cc] = *(const short8*)(qb_p + cc * 32);
  }

  float m[2][4], zz[2][4];
#pragma unroll
  for (int mi = 0; mi < 2; mi++)
#pragma unroll
    for (int r = 0; r < 4; r++) { m[mi][r] = -3.0e38f; zz[mi][r] = 0.f; }

  for (int kt = kbase; kt < kbase + 256; kt += 32) {
    __syncthreads();
#pragma unroll
    for (int i = 0; i < 2; i++) {
      int ch = i * 256 + tid;
      int krow = ch >> 4;
      int gcol = (ch & 15) ^ (krow & 7);  // xor-swizzle source column
      async_cp16(nk + (size_t)(kt + krow) * DIM + h * HD + gcol * 8,
                 Ks + ch * 8);
    }
    __syncthreads();
    short8 bk[2][4];
#pragma unroll
    for (int st = 0; st < 2; st++)
#pragma unroll
      for (int cc = 0; cc < 4; cc++) {
        int phys = (cc * 4 + q) ^ (lm & 7);
        bk[st][cc] = *(const short8*)(Ks + (st * 16 + lm) * 128 + phys * 8);
      }
#pragma unroll
    for (int mi = 0; mi < 2; mi++) {
      floatx4 a0 = (floatx4){0.f, 0.f, 0.f, 0.f};
      floatx4 a1 = (floatx4){0.f, 0.f, 0.f, 0.f};
#pragma unroll
      for (int cc = 0; cc < 4; cc++) {
        a0 = MFMA16(aq[mi][cc], bk[0][cc], a0);
        a1 = MFMA16(aq[mi][cc], bk[1][cc], a1);
      }
#pragma unroll
      for (int r = 0; r < 4; r++) {
        float s0 = a0[r] * f, s1 = a1[r] * f;
        float nm = fmaxf(m[mi][r], fmaxf(s0, s1));
        zz[mi][r] = zz[mi][r] * __expf(m[mi][r] - nm) + __expf(s0 - nm) +
                    __expf(s1 - nm);
        m[mi][r] = nm;
      }
    }
  }
  // merge (m,z) across the 16 lanes sharing each row
#pragma unroll
  for (int mk = 1; mk < 16; mk <<= 1)
#pragma unroll
    for (int mi = 0; mi < 2; mi++)
#pragma unroll
      for (int r = 0; r < 4; r++) {
        float om = __shfl_xor(m[mi][r], mk, 64);
        float oz = __shfl_xor(zz[mi][r], mk, 64);
        float nm = fmaxf(m[mi][r], om);
        zz[mi][r] = zz[mi][r] * __expf(m[mi][r] - nm) + oz * __expf(om - nm);
        m[mi][r] = nm;
      }
  if (lm == 0) {
#pragma unroll
    for (int mi = 0; mi < 2; mi++)
#pragma unroll
      for (int r = 0; r < 4; r++) {
        int row = mb + mi * 16 + q * 4 + r;
        float* p = pstats + (((size_t)h * SEQ + row) * 8 + chunk) * 2;
        p[0] = m[mi][r];
        p[1] = zz[mi][r];
      }
  }
}

// ---------------------------------------------------------------------------
// K3b: merge 8 partial stats per row -> stats[h][row][2], global minZ.
// ---------------------------------------------------------------------------
__global__ __launch_bounds__(256) void k_merge(
    const float* __restrict__ pstats, float* __restrict__ stats,
    unsigned int* __restrict__ minZ) {
  int idx = blockIdx.x * 256 + threadIdx.x;  // h*SEQ + row
  const float* p = pstats + (size_t)idx * 16;
  float M = -3.0e38f;
#pragma unroll
  for (int c = 0; c < 8; c++) M = fmaxf(M, p[c * 2]);
  float Z = 0.f;
#pragma unroll
  for (int c = 0; c < 8; c++) Z += p[c * 2 + 1] * __expf(p[c * 2] - M);
  stats[(size_t)idx * 2] = M;
  stats[(size_t)idx * 2 + 1] = Z;
  atomicMin(minZ, __float_as_uint(Z));
}

// ---------------------------------------------------------------------------
// K4: pass 2 — scores, quantize probs, PV. Split-K x2, 64 rows/block
// (16 rows/wave). Grid: (2*32, NH) = 768 blocks => 3 waves/SIMD.
// Swizzled Ks and Vs. __expf throughout. Same per-row math order as R16.
// ---------------------------------------------------------------------------
__global__ __launch_bounds__(256) void k_attn(
    const unsigned short* __restrict__ nq, const unsigned short* __restrict__ nk,
    const unsigned short* __restrict__ nvT,
    const unsigned int* __restrict__ scal, const unsigned int* __restrict__ minZ,
    const float* __restrict__ stats, float* __restrict__ attn0,
    float* __restrict__ attn1) {
  __shared__ unsigned short Ks[32 * 128];
  __shared__ unsigned short Vs[128 * 32];
  __shared__ unsigned short Pl[4][16 * 40];
  int h = blockIdx.y, tid = threadIdx.x, lane = tid & 63, w = tid >> 6;
  int lm = lane & 15, q = lane >> 4;
  int qb = blockIdx.x & 31, chunk = blockIdx.x >> 5;
  int mb = qb * 64 + w * 16;
  float* attn = chunk ? attn1 : attn0;
  float sv = __uint_as_float(scal[2]) / 127.f;
  float f = (__uint_as_float(scal[0]) / 127.f) *
            (__uint_as_float(scal[1]) / 127.f) * SCALEF;
  float sp = (1.f / __uint_as_float(*minZ)) / 127.f;
  float inv_sp = 1.f / sp;

  short8 aq[4];
  {
    const unsigned short* qb_p =
        nq + (size_t)(mb + lm) * DIM + h * HD + q * 8;
#pragma unroll
    for (int cc = 0; cc < 4; cc++) aq[cc] = *(const short8*)(qb_p + cc * 32);
  }
  float M[4], invZ[4];
#pragma unroll
  for (int r = 0; r < 4; r++) {
    int row = mb + q * 4 + r;
    M[r] = stats[((size_t)h * SEQ + row) * 2];
    invZ[r] = 1.f / stats[((size_t)h * SEQ + row) * 2 + 1];
  }
  floatx4 accO[8];
#pragma unroll
  for (int j = 0; j < 8; j++) accO[j] = (floatx4){0.f, 0.f, 0.f, 0.f};

  int kbase = chunk * 1024;
  for (int kt = kbase; kt < kbase + 1024; kt += 32) {
    __syncthreads();
#pragma unroll
    for (int i = 0; i < 2; i++) {
      int ch = i * 256 + tid;
      int krow = ch >> 4;
      int gcol = (ch & 15) ^ (krow & 7);
      async_cp16(nk + (size_t)(kt + krow) * DIM + h * HD + gcol * 8,
                 Ks + ch * 8);
      int d = ch >> 2;
      int vcol = (ch & 3) ^ ((d >> 1) & 3);
      async_cp16(nvT + (size_t)(h * HD + d) * SEQ + kt + vcol * 8,
                 Vs + ch * 8);
    }
    __syncthreads();
    short8 bk[2][4];
#pragma unroll
    for (int st = 0; st < 2; st++)
#pragma unroll
      for (int cc = 0; cc < 4; cc++) {
        int phys = (cc * 4 + q) ^ (lm & 7);
        bk[st][cc] = *(const short8*)(Ks + (st * 16 + lm) * 128 + phys * 8);
      }
#pragma unroll
    for (int st = 0; st < 2; st++) {
      floatx4 acc = (floatx4){0.f, 0.f, 0.f, 0.f};
#pragma unroll
      for (int cc = 0; cc < 4; cc++) acc = MFMA16(aq[cc], bk[st][cc], acc);
#pragma unroll
      for (int r = 0; r < 4; r++) {
        float t = __expf(acc[r] * f - M[r]);
        float n = rintf(t * invZ[r] * inv_sp);
        n = fminf(n, 127.f);
        Pl[w][(q * 4 + r) * 40 + st * 16 + lm] = f2bf(n);
      }
    }
    __syncthreads();
    short8 ap = *(const short8*)(&Pl[w][lm * 40 + q * 8]);
#pragma unroll
    for (int j = 0; j < 8; j++) {
      int d = j * 16 + lm;
      int vphys = q ^ ((d >> 1) & 3);
      short8 bv = *(const short8*)(Vs + d * 32 + vphys * 8);
      accO[j] = MFMA16(ap, bv, accO[j]);
    }
  }
  float osc = sp * sv;
#pragma unroll
  for (int j = 0; j < 8; j++)
#pragma unroll
    for (int r = 0; r < 4; r++)
      attn[(size_t)(mb + q * 4 + r) * DIM + h * HD + j * 16 + lm] =
          accO[j][r] * osc;
}

// ---------------------------------------------------------------------------
// K5: out-proj: out[m,n] = sum_c O[m,c]*Wo[n,c] + bo[n]. Split-MFMA.
// Same pipelined structure as K1; A from pre-tiled Oh/Ol. Grid: (12, 16).
// ---------------------------------------------------------------------------
__global__ __launch_bounds__(256) void k_gemm_out(
    const unsigned short* __restrict__ Oh, const unsigned short* __restrict__ Ol,
    const float* __restrict__ Wo, const float* __restrict__ bo,
    float* __restrict__ out) {
  __shared__ __align__(16) unsigned short Ahs[3][4096], Als[3][4096];
  __shared__ __align__(16) unsigned short Bhs[2][4096], Bls[2][4096];
  int tid = threadIdx.x;
  // bijective XCD swizzle: 192 blocks = 8 x 24
  int L = blockIdx.x + 12 * blockIdx.y;
  int L2 = (L & 7) * 24 + (L >> 3);
  int by2 = L2 & 15, bx2 = L2 >> 4;
  int n0 = bx2 * 128, m0 = by2 * 128;
  int lane = tid & 63, w = tid >> 6;
  int wr = w >> 1, wc = w & 1, lm = lane & 15, q = lane >> 4;

  floatx4 acc[4][4];
#pragma unroll
  for (int i = 0; i < 4; i++)
#pragma unroll
    for (int j = 0; j < 4; j++) acc[i][j] = (floatx4){0.f, 0.f, 0.f, 0.f};

  int rowA = tid >> 2, c8 = tid & 3;
  const float* pB0 = Wo + (size_t)(n0 + rowA) * DIM + c8 * 8;
  const float* pB1 = pB0 + (size_t)64 * DIM;
  size_t tb = (size_t)by2 * 48 * 4096;
  int sidx0 = tid, sidx1 = 256 + tid;
  int phA = (q ^ ((lm >> 1) & 3)) * 8;
  int mrbase = wr * 64 + lm;
  unsigned short* Abh = &Ahs[0][0];
  unsigned short* Abl = &Als[0][0];
  unsigned short* Bbh = &Bhs[0][0];
  unsigned short* Bbl = &Bls[0][0];
  const unsigned short* XH_ = Oh;
  const unsigned short* XL_ = Ol;

  float4 wA0, wA1, wA2, wA3, wB0, wB1, wB2, wB3;
  wB0 = *(const float4*)(pB0);
  wB1 = *(const float4*)(pB0 + 4);
  wB2 = *(const float4*)(pB1);
  wB3 = *(const float4*)(pB1 + 4);
  async_cp16(XH_ + tb + sidx0 * 8, Abh + sidx0 * 8);
  async_cp16(XL_ + tb + sidx0 * 8, Abl + sidx0 * 8);
  async_cp16(XH_ + tb + sidx1 * 8, Abh + sidx1 * 8);
  async_cp16(XL_ + tb + sidx1 * 8, Abl + sidx1 * 8);
  async_cp16(XH_ + tb + 4096 + sidx0 * 8, Abh + 4096 + sidx0 * 8);
  async_cp16(XL_ + tb + 4096 + sidx0 * 8, Abl + 4096 + sidx0 * 8);
  async_cp16(XH_ + tb + 4096 + sidx1 * 8, Abh + 4096 + sidx1 * 8);
  async_cp16(XL_ + tb + 4096 + sidx1 * 8, Abl + 4096 + sidx1 * 8);
  wA0 = *(const float4*)(pB0 + 32);
  wA1 = *(const float4*)(pB0 + 36);
  wA2 = *(const float4*)(pB1 + 32);
  wA3 = *(const float4*)(pB1 + 36);
  SPLIT_B(0, wB0, wB1, wB2, wB3);
  asm volatile("s_waitcnt vmcnt(8) lgkmcnt(0)" ::: "memory");
  __builtin_amdgcn_s_barrier();
  __builtin_amdgcn_sched_barrier(0);

  int scur = 0;
  for (int p = 0; p < 23; ++p) {
    GSTEP(2 * p, scur, wA0, wA1, wA2, wA3, wB0, wB1, wB2, wB3);
    scur = (scur + 1 == 3) ? 0 : scur + 1;
    GSTEP(2 * p + 1, scur, wB0, wB1, wB2, wB3, wA0, wA1, wA2, wA3);
    scur = (scur + 1 == 3) ? 0 : scur + 1;
  }
  COMPUTE_TILE(1, 0);
  SPLIT_B(1, wA0, wA1, wA2, wA3);
  asm volatile("s_waitcnt lgkmcnt(0)" ::: "memory");
  __builtin_amdgcn_s_barrier();
  __builtin_amdgcn_sched_barrier(0);
  COMPUTE_TILE(2, 1);

#pragma unroll
  for (int j = 0; j < 4; j++) {
    int col = n0 + wc * 64 + j * 16 + lm;
    float bias = bo[col];
#pragma unroll
    for (int i = 0; i < 4; i++) {
      int row = m0 + wr * 64 + i * 16 + q * 4;
#pragma unroll
      for (int r = 0; r < 4; r++)
        out[(size_t)(row + r) * DIM + col] = acc[i][j][r] + bias;
    }
  }
}

// ---------------------------------------------------------------------------
extern "C" void kernel_launch(void* const* d_in, const int* in_sizes, int n_in,
                              void* d_out, int out_size, void* d_ws, size_t ws_size,
                              hipStream_t stream) {
  float* out = (float*)d_out;
  bool sizes_ok = (n_in >= 6) && in_sizes && in_sizes[0] == SEQ * DIM &&
                  in_sizes[1] == DIM * DIM && in_sizes[2] == DIM * DIM &&
                  in_sizes[3] == DIM * DIM && in_sizes[4] == DIM * DIM &&
                  in_sizes[5] == DIM && out_size == SEQ * DIM;
  if (!sizes_ok) {
    k_fill<<<(out_size + 255) / 256, 256, 0, stream>>>(out, out_size, 1.0f);
    return;
  }
  if (ws_size < 50528272) {
    k_fill<<<(out_size + 255) / 256, 256, 0, stream>>>(out, out_size, 2.0f);
    return;
  }

  const float* x  = (const float*)d_in[0];
  const float* Wq = (const float*)d_in[1];
  const float* Wk = (const float*)d_in[2];
  const float* Wv = (const float*)d_in[3];
  const float* Wo = (const float*)d_in[4];
  const float* bo = (const float*)d_in[5];
  char* ws = (char*)d_ws;

  // Workspace layout (peak < 50.53 MB):
  float* qf = (float*)(ws);                                // 12,582,912 B
  float* kf = (float*)(ws + 12582912);                     // 12,582,912 B
  float* vf = (float*)(ws + 25165824);                     // 12,582,912 B
  unsigned short* nq  = (unsigned short*)(ws + 25165824);  // aliases vf (dead)
  float* pstats = (float*)(ws + 31457280);                 // 1,572,864 B
  unsigned short* nvT = (unsigned short*)(ws + 37748736);  // 6,291,456 B
  unsigned short* nk  = (unsigned short*)(ws + 44040192);  // 6,291,456 B
  // X-split tiled planes live in the nvT/nk slots until quant kernels run:
  unsigned short* Xh = nvT;   // dead after k_gemm_qkv
  unsigned short* Xl = nk;    // dead after k_gemm_qkv
  // attn-output tiled planes reuse the same slots after k_attn:
  unsigned short* Oh = nvT;   // written by k_split_o (nvT dead after k_attn)
  unsigned short* Ol = nk;    // written by k_split_o (nk dead after k_attn)
  float* attn0 = qf;                                       // aliases qf (dead)
  float* attn1 = kf;                                       // aliases kf (dead)
  float* stats = (float*)(ws + 50331648);                  // 196,608 B
  unsigned int* scal = (unsigned int*)(ws + 50528256);     // 16 B

  hipMemsetAsync(scal, 0, 12, stream);
  hipMemsetAsync(scal + 3, 0x7f, 4, stream);  // minZ init ~3.39e38

  k_split_x<<<dim3(48, 16), 256, 0, stream>>>(x, Xh, Xl);
  k_gemm_qkv<<<dim3(12, 16, 3), 256, 0, stream>>>(Xh, Xl, Wq, Wk, Wv, qf, kf,
                                                  vf, scal);
  k_quant_vT<<<dim3(SEQ / 64, HD / 64, NH), 256, 0, stream>>>(vf, scal, nvT);
  k_quant_qk<<<dim3((SEQ * DIM) / 1024, 2), 256, 0, stream>>>(qf, kf, scal, nq, nk);
  k_stats<<<dim3(8 * 16, NH), 256, 0, stream>>>(nq, nk, scal, pstats);
  k_merge<<<dim3(NH * SEQ / 256), 256, 0, stream>>>(pstats, stats, scal + 3);
  k_attn<<<dim3(2 * 32, NH), 256, 0, stream>>>(nq, nk, nvT, scal, scal + 3,
                                               stats, attn0, attn1);
  k_split_o<<<dim3(48, 16), 256, 0, stream>>>(attn0, attn1, Oh, Ol);
  k_gemm_out<<<dim3(12, 16), 256, 0, stream>>>(Oh, Ol, Wo, bo, out);
}

// Round 12
// 440.833 us; speedup vs baseline: 1.1065x; 1.0539x over previous
//
#include <hip/hip_runtime.h>
#include <stdint.h>

// B=1, L=2048, DIM=1536, H=12, HD=128. Inputs f32, output f32 (verified R6).
// R16: __expf => 472.8us best. R17/18: BN=64 falsified TLP-via-narrower-tile
// (FETCH doubled). R19: k_attn 16 rows/wave, 768 blocks (3 waves/SIMD) =>
// 464.6us best; lesson: these 2-phase loops respond to BLOCK-level TLP.
// R20: same lever on the last under-filled dispatch: k_gemm_out K-split x2
// (384 blocks, still one co-resident round, 24 iters/block) -> partials in
// qf/kf (dead after k_split_o), + fused merge+bias kernel (~6us). Only the
// out-proj K-sum order changes (f32 reorder ~1e-6 rel); upstream bit-identical.
#define SEQ 2048
#define DIM 1536
#define NH  12
#define HD  128
#define SCALEF 0.08838834764831845f  // 128^-0.5

typedef __attribute__((ext_vector_type(8))) short short8;
typedef __attribute__((ext_vector_type(4))) float floatx4;

#define MFMA16(a, b, c) __builtin_amdgcn_mfma_f32_16x16x32_bf16((a), (b), (c), 0, 0, 0)

__device__ __forceinline__ void async_cp16(const void* g, void* l) {
  __builtin_amdgcn_global_load_lds(
      (__attribute__((address_space(1))) unsigned int*)(g),
      (__attribute__((address_space(3))) unsigned int*)(l), 16, 0, 0);
}

__device__ __forceinline__ unsigned short f2bf(float f) {
  unsigned int u = __float_as_uint(f);
  u = (u + 0x7fff + ((u >> 16) & 1)) >> 16;  // RNE
  return (unsigned short)u;
}

// Split f32 -> hi (truncated bf16) + lo (RNE bf16 of residual).
__device__ __forceinline__ void split8v(const float* x, short8& h, short8& l) {
#pragma unroll
  for (int e = 0; e < 8; e++) {
    unsigned int u = __float_as_uint(x[e]);
    h[e] = (short)(u >> 16);
    float r = x[e] - __uint_as_float(u & 0xFFFF0000u);
    l[e] = (short)f2bf(r);
  }
}
__device__ __forceinline__ void split8(const float* g, short8& h, short8& l) {
  float4 f0 = *(const float4*)g, f1 = *(const float4*)(g + 4);
  float x[8] = {f0.x, f0.y, f0.z, f0.w, f1.x, f1.y, f1.z, f1.w};
  split8v(x, h, l);
}

__global__ __launch_bounds__(256) void k_fill(float* __restrict__ out, int n,
                                              float val) {
  int i = blockIdx.x * 256 + threadIdx.x;
  if (i < n) out[i] = val;
}

// ---------------------------------------------------------------------------
// K0a: pre-split X -> tiled bf16 planes. Tile (mb,ks) = 8KB contiguous,
// rows mb*128..+127 x k ks*32..+31, chunk-xor (p ^ (row>>1)&3) pre-applied.
// Grid: (48 ks, 16 mb).
// ---------------------------------------------------------------------------
__global__ __launch_bounds__(256) void k_split_x(
    const float* __restrict__ X, unsigned short* __restrict__ Xh,
    unsigned short* __restrict__ Xl) {
  int ks = blockIdx.x, mb = blockIdx.y, tid = threadIdx.x;
  size_t tb = ((size_t)mb * 48 + ks) * 4096;
#pragma unroll
  for (int i = 0; i < 2; i++) {
    int sidx = i * 256 + tid;
    int row = sidx >> 2, p = sidx & 3;
    int c = p ^ ((row >> 1) & 3);
    short8 h, l;
    split8(X + (size_t)(mb * 128 + row) * DIM + ks * 32 + c * 8, h, l);
    *(short8*)(Xh + tb + sidx * 8) = h;
    *(short8*)(Xl + tb + sidx * 8) = l;
  }
}

// ---------------------------------------------------------------------------
// K0b: pre-sum + split attn output -> tiled Oh/Ol (same layout as k_split_x).
// ---------------------------------------------------------------------------
__global__ __launch_bounds__(256) void k_split_o(
    const float* __restrict__ A0, const float* __restrict__ A1,
    unsigned short* __restrict__ Oh, unsigned short* __restrict__ Ol) {
  int ks = blockIdx.x, mb = blockIdx.y, tid = threadIdx.x;
  size_t tb = ((size_t)mb * 48 + ks) * 4096;
#pragma unroll
  for (int i = 0; i < 2; i++) {
    int sidx = i * 256 + tid;
    int row = sidx >> 2, p = sidx & 3;
    int c = p ^ ((row >> 1) & 3);
    size_t off = (size_t)(mb * 128 + row) * DIM + ks * 32 + c * 8;
    float4 x0 = *(const float4*)(A0 + off), x1 = *(const float4*)(A0 + off + 4);
    float4 y0 = *(const float4*)(A1 + off), y1 = *(const float4*)(A1 + off + 4);
    float xs[8] = {x0.x + y0.x, x0.y + y0.y, x0.z + y0.z, x0.w + y0.w,
                   x1.x + y1.x, x1.y + y1.y, x1.z + y1.z, x1.w + y1.w};
    short8 h, l;
    split8v(xs, h, l);
    *(short8*)(Oh + tb + sidx * 8) = h;
    *(short8*)(Ol + tb + sidx * 8) = l;
  }
}

// ---------------------------------------------------------------------------
// Pipelined split-MFMA GEMM step macros (shared by k_gemm_qkv / k_gemm_out).
// ---------------------------------------------------------------------------
#define COMPUTE_TILE(SA, SB)                                                  \
  {                                                                           \
    const unsigned short* Ah_ = Abh + (SA) * 4096;                            \
    const unsigned short* Al_ = Abl + (SA) * 4096;                            \
    const unsigned short* Bh_ = Bbh + (SB) * 4096;                            \
    const unsigned short* Bl_ = Bbl + (SB) * 4096;                            \
    short8 ah_[4], al_[4], bh_[4], bl_[4];                                    \
    _Pragma("unroll") for (int i_ = 0; i_ < 4; i_++) {                        \
      int off_ = (mrbase + i_ * 16) * 32 + phA;                               \
      ah_[i_] = *(const short8*)(Ah_ + off_);                                 \
      al_[i_] = *(const short8*)(Al_ + off_);                                 \
    }                                                                         \
    _Pragma("unroll") for (int j_ = 0; j_ < 4; j_++) {                        \
      int off_ = q * 1024 + (wc * 64 + j_ * 16 + lm) * 8;                     \
      bh_[j_] = *(const short8*)(Bh_ + off_);                                 \
      bl_[j_] = *(const short8*)(Bl_ + off_);                                 \
    }                                                                         \
    __builtin_amdgcn_s_setprio(1);                                            \
    _Pragma("unroll") for (int i_ = 0; i_ < 4; i_++)                          \
      _Pragma("unroll") for (int j_ = 0; j_ < 4; j_++) {                      \
        acc[i_][j_] = MFMA16(ah_[i_], bh_[j_], acc[i_][j_]);                  \
        acc[i_][j_] = MFMA16(ah_[i_], bl_[j_], acc[i_][j_]);                  \
        acc[i_][j_] = MFMA16(al_[i_], bh_[j_], acc[i_][j_]);                  \
      }                                                                       \
    __builtin_amdgcn_s_setprio(0);                                            \
  }

#define SPLIT_B(SB, S0x, S1x, S2x, S3x)                                       \
  {                                                                           \
    unsigned short* BhN_ = Bbh + (SB) * 4096;                                 \
    unsigned short* BlN_ = Bbl + (SB) * 4096;                                 \
    short8 h_, l_;                                                            \
    {                                                                         \
      float xs_[8] = {S0x.x, S0x.y, S0x.z, S0x.w,                             \
                      S1x.x, S1x.y, S1x.z, S1x.w};                            \
      split8v(xs_, h_, l_);                                                   \
      *(short8*)(BhN_ + c8 * 1024 + rowA * 8) = h_;                           \
      *(short8*)(BlN_ + c8 * 1024 + rowA * 8) = l_;                           \
    }                                                                         \
    {                                                                         \
      float xs_[8] = {S2x.x, S2x.y, S2x.z, S2x.w,                             \
                      S3x.x, S3x.y, S3x.z, S3x.w};                            \
      split8v(xs_, h_, l_);                                                   \
      *(short8*)(BhN_ + c8 * 1024 + (64 + rowA) * 8) = h_;                    \
      *(short8*)(BlN_ + c8 * 1024 + (64 + rowA) * 8) = l_;                    \
    }                                                                         \
  }

#define GSTEP(T, SCUR, S0x, S1x, S2x, S3x, L0x, L1x, L2x, L3x)                \
  {                                                                           \
    const int t_ = (T), sc_ = (SCUR);                                         \
    const int sn_ = sc_ >= 1 ? sc_ - 1 : 2; /* (sc_+2)%3 */                   \
    size_t tn_ = tb + (size_t)(t_ + 2) * 4096;                                \
    async_cp16(XH_ + tn_ + sidx0 * 8, Abh + sn_ * 4096 + sidx0 * 8);          \
    async_cp16(XL_ + tn_ + sidx0 * 8, Abl + sn_ * 4096 + sidx0 * 8);          \
    async_cp16(XH_ + tn_ + sidx1 * 8, Abh + sn_ * 4096 + sidx1 * 8);          \
    async_cp16(XL_ + tn_ + sidx1 * 8, Abl + sn_ * 4096 + sidx1 * 8);          \
    {                                                                         \
      int kn_ = (t_ + 2) * 32;                                                \
      L0x = *(const float4*)(pB0 + kn_);                                      \
      L1x = *(const float4*)(pB0 + kn_ + 4);                                  \
      L2x = *(const float4*)(pB1 + kn_);                                      \
      L3x = *(const float4*)(pB1 + kn_ + 4);                                  \
    }                                                                         \
    COMPUTE_TILE(sc_, (t_) & 1);                                              \
    SPLIT_B((t_ + 1) & 1, S0x, S1x, S2x, S3x);                                \
    asm volatile("s_waitcnt vmcnt(8) lgkmcnt(0)" ::: "memory");               \
    __builtin_amdgcn_s_barrier();                                             \
    __builtin_amdgcn_sched_barrier(0);                                        \
  }

#define GEMM_PRO()                                                            \
  wB0 = *(const float4*)(pB0);                                                \
  wB1 = *(const float4*)(pB0 + 4);                                            \
  wB2 = *(const float4*)(pB1);                                                \
  wB3 = *(const float4*)(pB1 + 4);                                            \
  async_cp16(XH_ + tb + sidx0 * 8, Abh + sidx0 * 8);                          \
  async_cp16(XL_ + tb + sidx0 * 8, Abl + sidx0 * 8);                          \
  async_cp16(XH_ + tb + sidx1 * 8, Abh + sidx1 * 8);                          \
  async_cp16(XL_ + tb + sidx1 * 8, Abl + sidx1 * 8);                          \
  async_cp16(XH_ + tb + 4096 + sidx0 * 8, Abh + 4096 + sidx0 * 8);            \
  async_cp16(XL_ + tb + 4096 + sidx0 * 8, Abl + 4096 + sidx0 * 8);            \
  async_cp16(XH_ + tb + 4096 + sidx1 * 8, Abh + 4096 + sidx1 * 8);            \
  async_cp16(XL_ + tb + 4096 + sidx1 * 8, Abl + 4096 + sidx1 * 8);            \
  wA0 = *(const float4*)(pB0 + 32);                                           \
  wA1 = *(const float4*)(pB0 + 36);                                           \
  wA2 = *(const float4*)(pB1 + 32);                                           \
  wA3 = *(const float4*)(pB1 + 36);                                           \
  SPLIT_B(0, wB0, wB1, wB2, wB3);                                             \
  asm volatile("s_waitcnt vmcnt(8) lgkmcnt(0)" ::: "memory");                 \
  __builtin_amdgcn_s_barrier();                                               \
  __builtin_amdgcn_sched_barrier(0);

// NIT2 = half the K-steps minus 1 pair-loop count. For NIT iters total:
// pair-loop runs (NIT-2)/2 times, then tail t=NIT-2 (even), final t=NIT-1.
#define GEMM_LOOP(NPAIR, TTAIL)                                               \
  int scur = 0;                                                               \
  for (int p = 0; p < (NPAIR); ++p) {                                         \
    GSTEP(2 * p, scur, wA0, wA1, wA2, wA3, wB0, wB1, wB2, wB3);               \
    scur = (scur + 1 == 3) ? 0 : scur + 1;                                    \
    GSTEP(2 * p + 1, scur, wB0, wB1, wB2, wB3, wA0, wA1, wA2, wA3);           \
    scur = (scur + 1 == 3) ? 0 : scur + 1;                                    \
  }                                                                           \
  COMPUTE_TILE((TTAIL) % 3, 0);                                               \
  SPLIT_B(1, wA0, wA1, wA2, wA3);                                             \
  asm volatile("s_waitcnt lgkmcnt(0)" ::: "memory");                          \
  __builtin_amdgcn_s_barrier();                                               \
  __builtin_amdgcn_sched_barrier(0);                                          \
  COMPUTE_TILE(((TTAIL) + 1) % 3, 1);

// ---------------------------------------------------------------------------
// K1: QKV projections: C[m,n] = sum_c X[m,c]*W[n,c]. Split-MFMA, 128x128
// tile, 3-deep A pipeline + W double-reg + counted vmcnt. Grid: (12,16,3).
// ---------------------------------------------------------------------------
__global__ __launch_bounds__(256) void k_gemm_qkv(
    const unsigned short* __restrict__ Xh, const unsigned short* __restrict__ Xl,
    const float* __restrict__ Wq, const float* __restrict__ Wk,
    const float* __restrict__ Wv, float* __restrict__ qf,
    float* __restrict__ kf, float* __restrict__ vf,
    unsigned int* __restrict__ scal) {
  __shared__ __align__(16) unsigned short Ahs[3][4096], Als[3][4096];
  __shared__ __align__(16) unsigned short Bhs[2][4096], Bls[2][4096];
  int tid = threadIdx.x;
  // bijective XCD swizzle: 576 blocks = 8 XCDs x 72.
  int L = blockIdx.x + 12 * blockIdx.y + 192 * blockIdx.z;
  int L2 = (L & 7) * 72 + (L >> 3);
  int by2 = L2 & 15, rest = L2 >> 4;
  int bx2 = rest % 12, z = rest / 12;
  const float* W = (z == 0) ? Wq : (z == 1) ? Wk : Wv;
  float* C = (z == 0) ? qf : (z == 1) ? kf : vf;
  int n0 = bx2 * 128, m0 = by2 * 128;
  int lane = tid & 63, w = tid >> 6;
  int wr = w >> 1, wc = w & 1, lm = lane & 15, q = lane >> 4;

  floatx4 acc[4][4];
#pragma unroll
  for (int i = 0; i < 4; i++)
#pragma unroll
    for (int j = 0; j < 4; j++) acc[i][j] = (floatx4){0.f, 0.f, 0.f, 0.f};

  int rowA = tid >> 2, c8 = tid & 3;
  const float* pB0 = W + (size_t)(n0 + rowA) * DIM + c8 * 8;
  const float* pB1 = pB0 + (size_t)64 * DIM;
  size_t tb = (size_t)by2 * 48 * 4096;
  int sidx0 = tid, sidx1 = 256 + tid;
  int phA = (q ^ ((lm >> 1) & 3)) * 8;
  int mrbase = wr * 64 + lm;
  unsigned short* Abh = &Ahs[0][0];
  unsigned short* Abl = &Als[0][0];
  unsigned short* Bbh = &Bhs[0][0];
  unsigned short* Bbl = &Bls[0][0];
  const unsigned short* XH_ = Xh;
  const unsigned short* XL_ = Xl;

  float4 wA0, wA1, wA2, wA3, wB0, wB1, wB2, wB3;
  GEMM_PRO();
  GEMM_LOOP(23, 46);

  float am = 0.f;
#pragma unroll
  for (int i = 0; i < 4; i++) {
    int row = m0 + wr * 64 + i * 16 + q * 4;
#pragma unroll
    for (int j = 0; j < 4; j++) {
      int col = n0 + wc * 64 + j * 16 + lm;
#pragma unroll
      for (int r = 0; r < 4; r++) {
        float v = acc[i][j][r];
        C[(size_t)(row + r) * DIM + col] = v;
        am = fmaxf(am, fabsf(v));
      }
    }
  }
#pragma unroll
  for (int mk = 32; mk >= 1; mk >>= 1) am = fmaxf(am, __shfl_xor(am, mk, 64));
  if (lane == 0) atomicMax(&scal[z], __float_as_uint(am));
}

// ---------------------------------------------------------------------------
// K2a: quantize + transpose V -> nvT[h][d][k] (bf16 integer values).
// ---------------------------------------------------------------------------
__global__ __launch_bounds__(256) void k_quant_vT(
    const float* __restrict__ vf, const unsigned int* __restrict__ scal,
    unsigned short* __restrict__ nvT) {
  __shared__ float T[64 * 65];
  int h = blockIdx.z, d0 = blockIdx.y * 64, k0 = blockIdx.x * 64;
  float s = __uint_as_float(scal[2]) / 127.f;
  int t = threadIdx.x;
#pragma unroll
  for (int i = 0; i < 16; i++) {
    int idx = i * 256 + t;
    int r = idx >> 6, c = idx & 63;
    float v = vf[(size_t)(k0 + r) * DIM + h * HD + d0 + c];
    T[r * 65 + c] = fminf(fmaxf(rintf(v / s), -128.f), 127.f);
  }
  __syncthreads();
#pragma unroll
  for (int i = 0; i < 16; i++) {
    int idx = i * 256 + t;
    int d = idx >> 6, r = idx & 63;
    nvT[(size_t)(h * HD + d0 + d) * SEQ + k0 + r] = f2bf(T[r * 65 + d]);
  }
}

// ---------------------------------------------------------------------------
// K2b: quantize q,k -> integer-valued bf16.
// ---------------------------------------------------------------------------
__global__ __launch_bounds__(256) void k_quant_qk(
    const float* __restrict__ qf, const float* __restrict__ kf,
    const unsigned int* __restrict__ scal,
    unsigned short* __restrict__ nq, unsigned short* __restrict__ nk) {
  int z = blockIdx.y;
  const float* src = z ? kf : qf;
  unsigned short* dst = z ? nk : nq;
  float s = __uint_as_float(scal[z]) / 127.f;
  size_t i = ((size_t)blockIdx.x * 256 + threadIdx.x) * 4;
  float4 v = *(const float4*)(src + i);
  ushort4 o;
  o.x = f2bf(fminf(fmaxf(rintf(v.x / s), -128.f), 127.f));
  o.y = f2bf(fminf(fmaxf(rintf(v.y / s), -128.f), 127.f));
  o.z = f2bf(fminf(fmaxf(rintf(v.z / s), -128.f), 127.f));
  o.w = f2bf(fminf(fmaxf(rintf(v.w / s), -128.f), 127.f));
  *(ushort4*)(dst + i) = o;
}

// ---------------------------------------------------------------------------
// K3: partial softmax stats, split-K x8, online per-lane (m,z), swizzled Ks.
// Grid: (8*16, NH). pstats[h][row][chunk][2]. __expf throughout.
// ---------------------------------------------------------------------------
__global__ __launch_bounds__(256) void k_stats(
    const unsigned short* __restrict__ nq, const unsigned short* __restrict__ nk,
    const unsigned int* __restrict__ scal, float* __restrict__ pstats) {
  __shared__ unsigned short Ks[32 * 128];
  int h = blockIdx.y, tid = threadIdx.x, lane = tid & 63, w = tid >> 6;
  int lm = lane & 15, q = lane >> 4;
  int qb = blockIdx.x & 15, chunk = blockIdx.x >> 4;
  int mb = qb * 128 + w * 32;
  int kbase = chunk * 256;
  float f = (__uint_as_float(scal[0]) / 127.f) *
            (__uint_as_float(scal[1]) / 127.f) * SCALEF;

  short8 aq[2][4];
#pragma unroll
  for (int mi = 0; mi < 2; mi++) {
    const unsigned short* qb_p =
        nq + (size_t)(mb + mi * 16 + lm) * DIM + h * HD + q * 8;
#pragma unroll
    for (int cc = 0; cc < 4; cc++) aq[mi][cc] = *(const short8*)(qb_p + cc * 32);
  }

  float m[2][4], zz[2][4];
#pragma unroll
  for (int mi = 0; mi < 2; mi++)
#pragma unroll
    for (int r = 0; r < 4; r++) { m[mi][r] = -3.0e38f; zz[mi][r] = 0.f; }

  for (int kt = kbase; kt < kbase + 256; kt += 32) {
    __syncthreads();
#pragma unroll
    for (int i = 0; i < 2; i++) {
      int ch = i * 256 + tid;
      int krow = ch >> 4;
      int gcol = (ch & 15) ^ (krow & 7);  // xor-swizzle source column
      async_cp16(nk + (size_t)(kt + krow) * DIM + h * HD + gcol * 8,
                 Ks + ch * 8);
    }
    __syncthreads();
    short8 bk[2][4];
#pragma unroll
    for (int st = 0; st < 2; st++)
#pragma unroll
      for (int cc = 0; cc < 4; cc++) {
        int phys = (cc * 4 + q) ^ (lm & 7);
        bk[st][cc] = *(const short8*)(Ks + (st * 16 + lm) * 128 + phys * 8);
      }
#pragma unroll
    for (int mi = 0; mi < 2; mi++) {
      floatx4 a0 = (floatx4){0.f, 0.f, 0.f, 0.f};
      floatx4 a1 = (floatx4){0.f, 0.f, 0.f, 0.f};
#pragma unroll
      for (int cc = 0; cc < 4; cc++) {
        a0 = MFMA16(aq[mi][cc], bk[0][cc], a0);
        a1 = MFMA16(aq[mi][cc], bk[1][cc], a1);
      }
#pragma unroll
      for (int r = 0; r < 4; r++) {
        float s0 = a0[r] * f, s1 = a1[r] * f;
        float nm = fmaxf(m[mi][r], fmaxf(s0, s1));
        zz[mi][r] = zz[mi][r] * __expf(m[mi][r] - nm) + __expf(s0 - nm) +
                    __expf(s1 - nm);
        m[mi][r] = nm;
      }
    }
  }
  // merge (m,z) across the 16 lanes sharing each row
#pragma unroll
  for (int mk = 1; mk < 16; mk <<= 1)
#pragma unroll
    for (int mi = 0; mi < 2; mi++)
#pragma unroll
      for (int r = 0; r < 4; r++) {
        float om = __shfl_xor(m[mi][r], mk, 64);
        float oz = __shfl_xor(zz[mi][r], mk, 64);
        float nm = fmaxf(m[mi][r], om);
        zz[mi][r] = zz[mi][r] * __expf(m[mi][r] - nm) + oz * __expf(om - nm);
        m[mi][r] = nm;
      }
  if (lm == 0) {
#pragma unroll
    for (int mi = 0; mi < 2; mi++)
#pragma unroll
      for (int r = 0; r < 4; r++) {
        int row = mb + mi * 16 + q * 4 + r;
        float* p = pstats + (((size_t)h * SEQ + row) * 8 + chunk) * 2;
        p[0] = m[mi][r];
        p[1] = zz[mi][r];
      }
  }
}

// ---------------------------------------------------------------------------
// K3b: merge 8 partial stats per row -> stats[h][row][2], global minZ.
// ---------------------------------------------------------------------------
__global__ __launch_bounds__(256) void k_merge(
    const float* __restrict__ pstats, float* __restrict__ stats,
    unsigned int* __restrict__ minZ) {
  int idx = blockIdx.x * 256 + threadIdx.x;  // h*SEQ + row
  const float* p = pstats + (size_t)idx * 16;
  float M = -3.0e38f;
#pragma unroll
  for (int c = 0; c < 8; c++) M = fmaxf(M, p[c * 2]);
  float Z = 0.f;
#pragma unroll
  for (int c = 0; c < 8; c++) Z += p[c * 2 + 1] * __expf(p[c * 2] - M);
  stats[(size_t)idx * 2] = M;
  stats[(size_t)idx * 2 + 1] = Z;
  atomicMin(minZ, __float_as_uint(Z));
}

// ---------------------------------------------------------------------------
// K4: pass 2 — scores, quantize probs, PV. Split-K x2, 64 rows/block
// (16 rows/wave). Grid: (2*32, NH) = 768 blocks => 3 waves/SIMD.
// ---------------------------------------------------------------------------
__global__ __launch_bounds__(256) void k_attn(
    const unsigned short* __restrict__ nq, const unsigned short* __restrict__ nk,
    const unsigned short* __restrict__ nvT,
    const unsigned int* __restrict__ scal, const unsigned int* __restrict__ minZ,
    const float* __restrict__ stats, float* __restrict__ attn0,
    float* __restrict__ attn1) {
  __shared__ unsigned short Ks[32 * 128];
  __shared__ unsigned short Vs[128 * 32];
  __shared__ unsigned short Pl[4][16 * 40];
  int h = blockIdx.y, tid = threadIdx.x, lane = tid & 63, w = tid >> 6;
  int lm = lane & 15, q = lane >> 4;
  int qb = blockIdx.x & 31, chunk = blockIdx.x >> 5;
  int mb = qb * 64 + w * 16;
  float* attn = chunk ? attn1 : attn0;
  float sv = __uint_as_float(scal[2]) / 127.f;
  float f = (__uint_as_float(scal[0]) / 127.f) *
            (__uint_as_float(scal[1]) / 127.f) * SCALEF;
  float sp = (1.f / __uint_as_float(*minZ)) / 127.f;
  float inv_sp = 1.f / sp;

  short8 aq[4];
  {
    const unsigned short* qb_p =
        nq + (size_t)(mb + lm) * DIM + h * HD + q * 8;
#pragma unroll
    for (int cc = 0; cc < 4; cc++) aq[cc] = *(const short8*)(qb_p + cc * 32);
  }
  float M[4], invZ[4];
#pragma unroll
  for (int r = 0; r < 4; r++) {
    int row = mb + q * 4 + r;
    M[r] = stats[((size_t)h * SEQ + row) * 2];
    invZ[r] = 1.f / stats[((size_t)h * SEQ + row) * 2 + 1];
  }
  floatx4 accO[8];
#pragma unroll
  for (int j = 0; j < 8; j++) accO[j] = (floatx4){0.f, 0.f, 0.f, 0.f};

  int kbase = chunk * 1024;
  for (int kt = kbase; kt < kbase + 1024; kt += 32) {
    __syncthreads();
#pragma unroll
    for (int i = 0; i < 2; i++) {
      int ch = i * 256 + tid;
      int krow = ch >> 4;
      int gcol = (ch & 15) ^ (krow & 7);
      async_cp16(nk + (size_t)(kt + krow) * DIM + h * HD + gcol * 8,
                 Ks + ch * 8);
      int d = ch >> 2;
      int vcol = (ch & 3) ^ ((d >> 1) & 3);
      async_cp16(nvT + (size_t)(h * HD + d) * SEQ + kt + vcol * 8,
                 Vs + ch * 8);
    }
    __syncthreads();
    short8 bk[2][4];
#pragma unroll
    for (int st = 0; st < 2; st++)
#pragma unroll
      for (int cc = 0; cc < 4; cc++) {
        int phys = (cc * 4 + q) ^ (lm & 7);
        bk[st][cc] = *(const short8*)(Ks + (st * 16 + lm) * 128 + phys * 8);
      }
#pragma unroll
    for (int st = 0; st < 2; st++) {
      floatx4 acc = (floatx4){0.f, 0.f, 0.f, 0.f};
#pragma unroll
      for (int cc = 0; cc < 4; cc++) acc = MFMA16(aq[cc], bk[st][cc], acc);
#pragma unroll
      for (int r = 0; r < 4; r++) {
        float t = __expf(acc[r] * f - M[r]);
        float n = rintf(t * invZ[r] * inv_sp);
        n = fminf(n, 127.f);
        Pl[w][(q * 4 + r) * 40 + st * 16 + lm] = f2bf(n);
      }
    }
    __syncthreads();
    short8 ap = *(const short8*)(&Pl[w][lm * 40 + q * 8]);
#pragma unroll
    for (int j = 0; j < 8; j++) {
      int d = j * 16 + lm;
      int vphys = q ^ ((d >> 1) & 3);
      short8 bv = *(const short8*)(Vs + d * 32 + vphys * 8);
      accO[j] = MFMA16(ap, bv, accO[j]);
    }
  }
  float osc = sp * sv;
#pragma unroll
  for (int j = 0; j < 8; j++)
#pragma unroll
    for (int r = 0; r < 4; r++)
      attn[(size_t)(mb + q * 4 + r) * DIM + h * HD + j * 16 + lm] =
          accO[j][r] * osc;
}

// ---------------------------------------------------------------------------
// K5: out-proj partials: Cp[m,n] = sum_{c in half} O[m,c]*Wo[n,c].
// K-split x2 -> qf (chunk0) / kf (chunk1). Grid: 384 = 8 XCD x 48.
// ---------------------------------------------------------------------------
__global__ __launch_bounds__(256) void k_gemm_out(
    const unsigned short* __restrict__ Oh, const unsigned short* __restrict__ Ol,
    const float* __restrict__ Wo, float* __restrict__ P0,
    float* __restrict__ P1) {
  __shared__ __align__(16) unsigned short Ahs[3][4096], Als[3][4096];
  __shared__ __align__(16) unsigned short Bhs[2][4096], Bls[2][4096];
  int tid = threadIdx.x;
  int L = blockIdx.x;                       // 384 = 8 x 48 (bijective)
  int L2 = (L & 7) * 48 + (L >> 3);
  int kc = L2 & 1, rest = L2 >> 1;          // rest 0..191
  int by2 = rest & 15, bx2 = rest >> 4;     // bx2 0..11
  float* C = kc ? P1 : P0;
  int n0 = bx2 * 128, m0 = by2 * 128;
  int lane = tid & 63, w = tid >> 6;
  int wr = w >> 1, wc = w & 1, lm = lane & 15, q = lane >> 4;

  floatx4 acc[4][4];
#pragma unroll
  for (int i = 0; i < 4; i++)
#pragma unroll
    for (int j = 0; j < 4; j++) acc[i][j] = (floatx4){0.f, 0.f, 0.f, 0.f};

  int rowA = tid >> 2, c8 = tid & 3;
  const float* pB0 = Wo + (size_t)(n0 + rowA) * DIM + kc * 768 + c8 * 8;
  const float* pB1 = pB0 + (size_t)64 * DIM;
  size_t tb = ((size_t)by2 * 48 + kc * 24) * 4096;
  int sidx0 = tid, sidx1 = 256 + tid;
  int phA = (q ^ ((lm >> 1) & 3)) * 8;
  int mrbase = wr * 64 + lm;
  unsigned short* Abh = &Ahs[0][0];
  unsigned short* Abl = &Als[0][0];
  unsigned short* Bbh = &Bhs[0][0];
  unsigned short* Bbl = &Bls[0][0];
  const unsigned short* XH_ = Oh;
  const unsigned short* XL_ = Ol;

  float4 wA0, wA1, wA2, wA3, wB0, wB1, wB2, wB3;
  GEMM_PRO();
  GEMM_LOOP(11, 22);

#pragma unroll
  for (int j = 0; j < 4; j++) {
    int col = n0 + wc * 64 + j * 16 + lm;
#pragma unroll
    for (int i = 0; i < 4; i++) {
      int row = m0 + wr * 64 + i * 16 + q * 4;
#pragma unroll
      for (int r = 0; r < 4; r++)
        C[(size_t)(row + r) * DIM + col] = acc[i][j][r];
    }
  }
}

// ---------------------------------------------------------------------------
// K5b: merge the two out-proj partials + bias -> out.
// ---------------------------------------------------------------------------
__global__ __launch_bounds__(256) void k_merge_out(
    const float* __restrict__ P0, const float* __restrict__ P1,
    const float* __restrict__ bo, float* __restrict__ out) {
  size_t i = ((size_t)blockIdx.x * 256 + threadIdx.x) * 4;
  int col = (int)(i % DIM);
  float4 a = *(const float4*)(P0 + i);
  float4 b = *(const float4*)(P1 + i);
  float4 bb = *(const float4*)(bo + col);
  float4 o;
  o.x = a.x + b.x + bb.x;
  o.y = a.y + b.y + bb.y;
  o.z = a.z + b.z + bb.z;
  o.w = a.w + b.w + bb.w;
  *(float4*)(out + i) = o;
}

// ---------------------------------------------------------------------------
extern "C" void kernel_launch(void* const* d_in, const int* in_sizes, int n_in,
                              void* d_out, int out_size, void* d_ws, size_t ws_size,
                              hipStream_t stream) {
  float* out = (float*)d_out;
  bool sizes_ok = (n_in >= 6) && in_sizes && in_sizes[0] == SEQ * DIM &&
                  in_sizes[1] == DIM * DIM && in_sizes[2] == DIM * DIM &&
                  in_sizes[3] == DIM * DIM && in_sizes[4] == DIM * DIM &&
                  in_sizes[5] == DIM && out_size == SEQ * DIM;
  if (!sizes_ok) {
    k_fill<<<(out_size + 255) / 256, 256, 0, stream>>>(out, out_size, 1.0f);
    return;
  }
  if (ws_size < 50528272) {
    k_fill<<<(out_size + 255) / 256, 256, 0, stream>>>(out, out_size, 2.0f);
    return;
  }

  const float* x  = (const float*)d_in[0];
  const float* Wq = (const float*)d_in[1];
  const float* Wk = (const float*)d_in[2];
  const float* Wv = (const float*)d_in[3];
  const float* Wo = (const float*)d_in[4];
  const float* bo = (const float*)d_in[5];
  char* ws = (char*)d_ws;

  // Workspace layout (peak < 50.53 MB):
  float* qf = (float*)(ws);                                // 12,582,912 B
  float* kf = (float*)(ws + 12582912);                     // 12,582,912 B
  float* vf = (float*)(ws + 25165824);                     // 12,582,912 B
  unsigned short* nq  = (unsigned short*)(ws + 25165824);  // aliases vf (dead)
  float* pstats = (float*)(ws + 31457280);                 // 1,572,864 B
  unsigned short* nvT = (unsigned short*)(ws + 37748736);  // 6,291,456 B
  unsigned short* nk  = (unsigned short*)(ws + 44040192);  // 6,291,456 B
  // X-split tiled planes live in the nvT/nk slots until quant kernels run:
  unsigned short* Xh = nvT;   // dead after k_gemm_qkv
  unsigned short* Xl = nk;    // dead after k_gemm_qkv
  // attn-output tiled planes reuse the same slots after k_attn:
  unsigned short* Oh = nvT;   // written by k_split_o (nvT dead after k_attn)
  unsigned short* Ol = nk;    // written by k_split_o (nk dead after k_attn)
  float* attn0 = qf;                                       // aliases qf (dead)
  float* attn1 = kf;                                       // aliases kf (dead)
  // out-proj K-split partials reuse qf/kf (dead after k_split_o):
  float* outP0 = qf;
  float* outP1 = kf;
  float* stats = (float*)(ws + 50331648);                  // 196,608 B
  unsigned int* scal = (unsigned int*)(ws + 50528256);     // 16 B

  hipMemsetAsync(scal, 0, 12, stream);
  hipMemsetAsync(scal + 3, 0x7f, 4, stream);  // minZ init ~3.39e38

  k_split_x<<<dim3(48, 16), 256, 0, stream>>>(x, Xh, Xl);
  k_gemm_qkv<<<dim3(12, 16, 3), 256, 0, stream>>>(Xh, Xl, Wq, Wk, Wv, qf, kf,
                                                  vf, scal);
  k_quant_vT<<<dim3(SEQ / 64, HD / 64, NH), 256, 0, stream>>>(vf, scal, nvT);
  k_quant_qk<<<dim3((SEQ * DIM) / 1024, 2), 256, 0, stream>>>(qf, kf, scal, nq, nk);
  k_stats<<<dim3(8 * 16, NH), 256, 0, stream>>>(nq, nk, scal, pstats);
  k_merge<<<dim3(NH * SEQ / 256), 256, 0, stream>>>(pstats, stats, scal + 3);
  k_attn<<<dim3(2 * 32, NH), 256, 0, stream>>>(nq, nk, nvT, scal, scal + 3,
                                               stats, attn0, attn1);
  k_split_o<<<dim3(48, 16), 256, 0, stream>>>(attn0, attn1, Oh, Ol);
  k_gemm_out<<<dim3(384), 256, 0, stream>>>(Oh, Ol, Wo, outP0, outP1);
  k_merge_out<<<dim3(SEQ * DIM / 1024), 256, 0, stream>>>(outP0, outP1, bo, out);
}